// Round 12
// baseline (1064.879 us; speedup 1.0000x reference)
//
#include <hip/hip_runtime.h>
#include <hip/hip_bf16.h>
#include <math.h>

// ---------------------------------------------------------------------------
// CrossAttentionBlock on MI355X (gfx950) — round 11: GEMM reverted to the
// proven r5 2-phase BK=64 template (r6 depth-2 and r10 BK=32 both measured
// worse). Attention rebuilt barrier-free: V^T in per-wave REGISTERS (no LDS
// staging, no __syncthreads) so all waves run fully async; K single-buffer
// reuse keeps r7's issue-early latency hiding within the VGPR budget.
// B=4 N=2048 M=1024 C=1024 H=16 HD=64 HID=4096
// ---------------------------------------------------------------------------

typedef __attribute__((ext_vector_type(8))) short bf16x8;   // 8 bf16 in 4 VGPRs
typedef __attribute__((ext_vector_type(4))) short s16x4;    // 4 bf16 (8B)
typedef __attribute__((ext_vector_type(4))) float f32x4;

#define DEV __device__ __forceinline__

DEV unsigned short f2us(float f) {
  __hip_bfloat16 h = __float2bfloat16(f);
  return __builtin_bit_cast(unsigned short, h);
}

DEV void gload_lds16(const void* g, void* l) {
  __builtin_amdgcn_global_load_lds((const __attribute__((address_space(1))) void*)g,
                                   (__attribute__((address_space(3))) void*)l, 16, 0, 0);
}

#define MFMA_BF16_16x16x32 __builtin_amdgcn_mfma_f32_16x16x32_bf16
#define WAITV0 asm volatile("s_waitcnt vmcnt(0)" ::: "memory")

// ------------------------- elementwise converts ----------------------------

__global__ __launch_bounds__(256) void cvt_f32_bf16(const float* __restrict__ in,
                                                    __hip_bfloat16* __restrict__ out,
                                                    long n) {
  long i = ((long)blockIdx.x * blockDim.x + threadIdx.x) * 4;
  if (i + 3 < n) {
    float4 v = *(const float4*)(in + i);
    out[i + 0] = __float2bfloat16(v.x);
    out[i + 1] = __float2bfloat16(v.y);
    out[i + 2] = __float2bfloat16(v.z);
    out[i + 3] = __float2bfloat16(v.w);
  }
}

// w (K,N) fp32 row-major -> wT (N,K) bf16 row-major
__global__ __launch_bounds__(256) void transpose_cvt(const float* __restrict__ w,
                                                     __hip_bfloat16* __restrict__ wT,
                                                     int K, int N) {
  __shared__ float tile[32][33];
  int n0 = blockIdx.x * 32, k0 = blockIdx.y * 32;
  int tx = threadIdx.x, ty = threadIdx.y;
  #pragma unroll
  for (int i = 0; i < 32; i += 8)
    tile[ty + i][tx] = w[(long)(k0 + ty + i) * N + n0 + tx];
  __syncthreads();
  #pragma unroll
  for (int i = 0; i < 32; i += 8)
    wT[(long)(n0 + ty + i) * K + k0 + tx] = __float2bfloat16(tile[tx][ty + i]);
}

// V (strided, bf16) -> V^T tiled [bh][Nkv/64][64 d][72 kv(padded)] (bf16)
__global__ __launch_bounds__(256) void transpose_v(const __hip_bfloat16* __restrict__ v,
                                                   long vBatch, long vRow,
                                                   __hip_bfloat16* __restrict__ vt,
                                                   int Nkv) {
  __shared__ unsigned short tile[32][36];
  int bh = blockIdx.z;
  int b = bh >> 4, h = bh & 15;
  int kv0 = blockIdx.x * 32;
  int d0 = blockIdx.y * 32;
  int tx = threadIdx.x, ty = threadIdx.y;   // (32,8)
  const __hip_bfloat16* src = v + (long)b * vBatch + h * 64 + d0;
  #pragma unroll
  for (int i = 0; i < 32; i += 8)
    tile[ty + i][tx] = __builtin_bit_cast(unsigned short, src[(long)(kv0 + ty + i) * vRow + tx]);
  __syncthreads();
  unsigned short* dst = (unsigned short*)vt + ((long)bh * (Nkv >> 6) + (kv0 >> 6)) * 4608 + (kv0 & 32) + tx;
  #pragma unroll
  for (int i = 0; i < 32; i += 8)
    dst[(long)(d0 + ty + i) * 72] = tile[tx][ty + i];
}

// ------------------------------ LN + RoPE ----------------------------------
__global__ __launch_bounds__(256) void ln_rope(__hip_bfloat16* __restrict__ buf,
                                               const float* __restrict__ rope,
                                               const float* __restrict__ g0,
                                               const float* __restrict__ b0,
                                               const float* __restrict__ g1,
                                               const float* __restrict__ b1,
                                               int Rows, int W,
                                               long rowStride, long whichStride,
                                               int ropeMask, long total) {
  int lane = threadIdx.x & 63;
  int wv = threadIdx.x >> 6;
  long id = (long)blockIdx.x * 4 + wv;
  if (id >= total) return;
  int which = (int)(id % W);
  long t = id / W;
  int h = (int)(t & 15); t >>= 4;
  int n = (int)(t % Rows);
  int b = (int)(t / Rows);
  __hip_bfloat16* p = buf + ((long)b * Rows + n) * rowStride + (long)which * whichStride + h * 64 + lane;
  float v = __bfloat162float(*p);
  float s = v;
  #pragma unroll
  for (int m = 32; m; m >>= 1) s += __shfl_xor(s, m);
  float mean = s * (1.f / 64.f);
  float d = v - mean;
  float q = d * d;
  #pragma unroll
  for (int m = 32; m; m >>= 1) q += __shfl_xor(q, m);
  float rstd = rsqrtf(q * (1.f / 64.f) + 1e-6f);
  const float* g = which ? g1 : g0;
  const float* bb = which ? b1 : b0;
  float xn = d * rstd * g[lane] + bb[lane];
  if ((ropeMask >> which) & 1) {
    float partner = __shfl_xor(xn, 1);
    float sn = rope[(long)n * 128 + lane];
    float cs = rope[(long)n * 128 + 64 + lane];
    xn = (lane & 1) ? (xn * cs + partner * sn) : (xn * cs - partner * sn);
  }
  *p = __float2bfloat16(xn);
}

// --------------------- epilogue helper (shared by GEMMs) -------------------
template <int EPI>
DEV void epi_store(long idx, long col, float v,
                   float* __restrict__ out_f, __hip_bfloat16* __restrict__ out_b,
                   const float* __restrict__ bias, const float* __restrict__ scale,
                   const float* __restrict__ gate, const float* __restrict__ resid,
                   const __hip_bfloat16* __restrict__ mulin) {
  if constexpr (EPI == 0) {
    out_b[idx] = __float2bfloat16(v);
  } else if constexpr (EPI == 1) {
    float r = scale[col] * (v + bias[col]) + resid[idx];
    out_f[idx] = r;
    out_b[idx] = __float2bfloat16(r);
  } else if constexpr (EPI == 2) {
    float r = scale[col] * ((v + bias[col]) * tanhf(gate[col])) + resid[idx];
    out_f[idx] = r;
    out_b[idx] = __float2bfloat16(r);
  } else if constexpr (EPI == 3) {
    float z = v + bias[col];
    out_b[idx] = __float2bfloat16(z / (1.f + expf(-z)));
  } else if constexpr (EPI == 4) {
    float z = (v + bias[col]) * __bfloat162float(mulin[idx]);
    out_b[idx] = __float2bfloat16(z);
  } else {
    out_f[idx] = scale[col] * (v + bias[col]) + resid[idx];
  }
}

// ------------------------------ GEMM 128² (legacy, small shapes) -----------
template <int EPI>
__global__ __launch_bounds__(256) void gemm128(const __hip_bfloat16* __restrict__ A,
                                               const __hip_bfloat16* __restrict__ Bt,
                                               int M, int N, int K,
                                               float* __restrict__ out_f,
                                               __hip_bfloat16* __restrict__ out_b,
                                               const float* __restrict__ bias,
                                               const float* __restrict__ scale,
                                               const float* __restrict__ gate,
                                               const float* __restrict__ resid,
                                               const __hip_bfloat16* __restrict__ mulin) {
  __shared__ unsigned short As[128 * 32];
  __shared__ unsigned short Bs[128 * 32];
  int t = threadIdx.x;
  int l = t & 63;
  int w = t >> 6;
  int wr = w >> 1, wc = w & 1;
  long bm = blockIdx.x, bn = blockIdx.y;
  const __hip_bfloat16* Ab = A + bm * 128 * (long)K;
  const __hip_bfloat16* Bb = Bt + bn * 128 * (long)K;

  f32x4 acc[4][4] = {};

  for (int k0 = 0; k0 < K; k0 += 32) {
    #pragma unroll
    for (int j = 0; j < 2; j++) {
      int c = j * 256 + t;
      int row = c >> 2;
      int ko = (c & 3) * 8;
      gload_lds16(Ab + (long)row * K + k0 + ko, &As[c * 8]);
      gload_lds16(Bb + (long)row * K + k0 + ko, &Bs[c * 8]);
    }
    __syncthreads();
    bf16x8 af[4], bfg[4];
    #pragma unroll
    for (int m = 0; m < 4; m++)
      af[m] = *(const bf16x8*)&As[(wr * 64 + m * 16 + (l & 15)) * 32 + (l >> 4) * 8];
    #pragma unroll
    for (int n = 0; n < 4; n++)
      bfg[n] = *(const bf16x8*)&Bs[(wc * 64 + n * 16 + (l & 15)) * 32 + (l >> 4) * 8];
    #pragma unroll
    for (int m = 0; m < 4; m++)
      #pragma unroll
      for (int n = 0; n < 4; n++)
        acc[m][n] = MFMA_BF16_16x16x32(af[m], bfg[n], acc[m][n], 0, 0, 0);
    __syncthreads();
  }

  #pragma unroll
  for (int m = 0; m < 4; m++)
    #pragma unroll
    for (int n = 0; n < 4; n++)
      #pragma unroll
      for (int i = 0; i < 4; i++) {
        long row = bm * 128 + wr * 64 + m * 16 + (l >> 4) * 4 + i;
        long col = bn * 128 + wc * 64 + n * 16 + (l & 15);
        epi_store<EPI>(row * (long)N + col, col, acc[m][n][i],
                       out_f, out_b, bias, scale, gate, resid, mulin);
      }
}

// --------------- GEMM BMx256, BK=64, 2-phase (T3 minimum, r5) --------------
// 512 threads = 8 waves (2 M x 4 N). Double-buffered LDS; per K-tile:
// {stage(t+1) -> ds_read frags -> setprio MFMA -> vmcnt(0) -> s_barrier}.
// 3-bit chunk swizzle (c ^= row&7) on BOTH gload source and ds_read address.
template <int BM, int EPI>
__global__ __launch_bounds__(512, 2) void gemm2ph(const __hip_bfloat16* __restrict__ A,
                                                  const __hip_bfloat16* __restrict__ Bt,
                                                  int M, int N, int K,
                                                  float* __restrict__ out_f,
                                                  __hip_bfloat16* __restrict__ out_b,
                                                  const float* __restrict__ bias,
                                                  const float* __restrict__ scale,
                                                  const float* __restrict__ gate,
                                                  const float* __restrict__ resid,
                                                  const __hip_bfloat16* __restrict__ mulin) {
  constexpr int MF = BM / 32;          // m-frags per wave (8 or 4)
  constexpr int WRS = BM / 2;          // wave row span
  constexpr int AJ = BM * 8 / 512;     // A chunks per thread (4 or 2)
  __shared__ __align__(16) unsigned short As[2][BM * 64];
  __shared__ __align__(16) unsigned short Bs[2][256 * 64];

  int t = threadIdx.x;
  int l = t & 63, w = t >> 6;
  int lo = l & 15, hi = l >> 4;
  int wr = w >> 2, wc = w & 3;         // 2 x 4 waves
  long bm = blockIdx.x, bn = blockIdx.y;
  const __hip_bfloat16* Ab = A + bm * BM * (long)K;
  const __hip_bfloat16* Bb = Bt + bn * 256 * (long)K;
  int nt = K >> 6;

  auto stage = [&](int kt, int buf) {
    long kb = (long)kt * 64;
    #pragma unroll
    for (int j = 0; j < AJ; j++) {
      int q = j * 512 + t;
      int row = q >> 3, c = (q & 7) ^ (row & 7);
      gload_lds16(Ab + (long)row * K + kb + c * 8, &As[buf][q * 8]);
    }
    #pragma unroll
    for (int j = 0; j < 4; j++) {
      int q = j * 512 + t;
      int row = q >> 3, c = (q & 7) ^ (row & 7);
      gload_lds16(Bb + (long)row * K + kb + c * 8, &Bs[buf][q * 8]);
    }
  };

  f32x4 acc[MF][4] = {};

  stage(0, 0);
  WAITV0;
  __builtin_amdgcn_s_barrier();

  for (int kt = 0; kt < nt; ++kt) {
    int cur = kt & 1;
    if (kt + 1 < nt) stage(kt + 1, cur ^ 1);

    #pragma unroll
    for (int ks = 0; ks < 2; ks++) {
      bf16x8 bfrag[4];
      #pragma unroll
      for (int n = 0; n < 4; n++) {
        int rb = wc * 64 + n * 16 + lo;
        bfrag[n] = *(const bf16x8*)&Bs[cur][rb * 64 + (((ks << 2) | hi) ^ (rb & 7)) * 8];
      }
      #pragma unroll
      for (int mg = 0; mg < MF; mg += 4) {
        bf16x8 afrag[4];
        #pragma unroll
        for (int m = 0; m < 4; m++) {
          int ra = wr * WRS + (mg + m) * 16 + lo;
          afrag[m] = *(const bf16x8*)&As[cur][ra * 64 + (((ks << 2) | hi) ^ (ra & 7)) * 8];
        }
        __builtin_amdgcn_s_setprio(1);
        #pragma unroll
        for (int m = 0; m < 4; m++)
          #pragma unroll
          for (int n = 0; n < 4; n++)
            acc[mg + m][n] = MFMA_BF16_16x16x32(afrag[m], bfrag[n], acc[mg + m][n], 0, 0, 0);
        __builtin_amdgcn_s_setprio(0);
      }
    }

    if (kt + 1 < nt) {
      WAITV0;                          // next tile fully in LDS (issued early)
      __builtin_amdgcn_s_barrier();    // all waves' reads of cur done too
    }
  }

  #pragma unroll
  for (int m = 0; m < MF; m++)
    #pragma unroll
    for (int n = 0; n < 4; n++)
      #pragma unroll
      for (int i = 0; i < 4; i++) {
        long row = bm * BM + wr * WRS + m * 16 + hi * 4 + i;
        long col = bn * 256 + wc * 64 + n * 16 + lo;
        epi_store<EPI>(row * (long)N + col, col, acc[m][n][i],
                       out_f, out_b, bias, scale, gate, resid, mulin);
      }
}

// ---------------------------- attention ------------------------------------
// BARRIER-FREE: 4 fully independent waves/block, 32 q-rows/wave, KVBLK=64.
// Swapped QK^T + defer-max softmax (r7). V^T read straight into registers
// (vg[4][2], L2-hot) — no LDS V staging, no __syncthreads. K single-buffer:
// K(t+1) loads issued into the same regs right after QK^T(t) consumes them
// (HW scoreboard orders the WAR), landing during softmax+PV. P goes through
// per-wave private LDS (lgkmcnt only).
__global__ __launch_bounds__(256, 3) void attn32(const __hip_bfloat16* __restrict__ qB, long qBatch, long qRow,
                                                 const __hip_bfloat16* __restrict__ kB, long kBatch, long kRow,
                                                 const __hip_bfloat16* __restrict__ vt,
                                                 __hip_bfloat16* __restrict__ out, int Nq, int Nkv) {
  const float SC2 = 0.125f * 1.44269504089f;   // scale * log2(e)
  int t = threadIdx.x;
  int l = t & 63, w = t >> 6;
  int lo = l & 15, hi = l >> 4;
  int nQC = Nq >> 7;
  int qc = blockIdx.x % nQC;
  int bh = blockIdx.x / nQC;
  int h = bh & 15, b = bh >> 4;
  int q0 = qc * 128 + w * 32;

  __shared__ unsigned short P_all[4][32 * 72];   // per-wave private
  unsigned short* P = P_all[w];

  bf16x8 qf[2][2];
#pragma unroll
  for (int qs = 0; qs < 2; qs++) {
    const __hip_bfloat16* qp = qB + (long)b * qBatch + (long)(q0 + qs * 16 + lo) * qRow + h * 64 + hi * 8;
    qf[qs][0] = *(const bf16x8*)qp;
    qf[qs][1] = *(const bf16x8*)(qp + 32);
  }

  float mrow[2] = {-INFINITY, -INFINITY};
  float lsum[2] = {0.f, 0.f};
  f32x4 acc[2][4] = {};
  const f32x4 fz = {0.f, 0.f, 0.f, 0.f};

  const __hip_bfloat16* kbase = kB + (long)b * kBatch + h * 64 + hi * 8;
  int nt = Nkv >> 6;
  const unsigned short* vtb = (const unsigned short*)vt + (long)bh * nt * 4608;

  bf16x8 kg[4][2], vg[4][2];

  auto loadK = [&](int tile) {
#pragma unroll
    for (int g = 0; g < 4; g++) {
      const __hip_bfloat16* kp = kbase + (long)(tile * 64 + g * 16 + lo) * kRow;
      kg[g][0] = *(const bf16x8*)kp;
      kg[g][1] = *(const bf16x8*)(kp + 32);
    }
  };
  auto loadV = [&](int tile) {   // V^T tiled [64 d][72 kv]: row d=tt*16+lo, kv=half*32+hi*8
    const unsigned short* src = vtb + (long)tile * 4608;
#pragma unroll
    for (int tt = 0; tt < 4; tt++) {
      const unsigned short* vp = src + (tt * 16 + lo) * 72 + hi * 8;
      vg[tt][0] = *(const bf16x8*)vp;
      vg[tt][1] = *(const bf16x8*)(vp + 32);
    }
  };

  loadK(0);
  loadV(0);

  for (int it = 0; it < nt; ++it) {
    // QK^T (waits on kg loads issued last iteration)
    f32x4 ST[2][4];
#pragma unroll
    for (int qs = 0; qs < 2; qs++)
#pragma unroll
      for (int g = 0; g < 4; g++) {
        f32x4 s0 = MFMA_BF16_16x16x32(kg[g][0], qf[qs][0], fz, 0, 0, 0);
        ST[qs][g] = MFMA_BF16_16x16x32(kg[g][1], qf[qs][1], s0, 0, 0, 0);
      }
    if (it + 1 < nt) loadK(it + 1);      // WAR on kg — lands during smax+PV

    // online softmax (swapped layout: lane owns q=lo, 32 kv values in regs)
#pragma unroll
    for (int qs = 0; qs < 2; qs++) {
      float mg0 = fmaxf(fmaxf(ST[qs][0][0], ST[qs][0][1]), fmaxf(ST[qs][0][2], ST[qs][0][3]));
      float mg1 = fmaxf(fmaxf(ST[qs][1][0], ST[qs][1][1]), fmaxf(ST[qs][1][2], ST[qs][1][3]));
      float mg2 = fmaxf(fmaxf(ST[qs][2][0], ST[qs][2][1]), fmaxf(ST[qs][2][2], ST[qs][2][3]));
      float mg3 = fmaxf(fmaxf(ST[qs][3][0], ST[qs][3][1]), fmaxf(ST[qs][3][2], ST[qs][3][3]));
      float rm = fmaxf(fmaxf(mg0, mg1), fmaxf(mg2, mg3)) * SC2;
      rm = fmaxf(rm, __shfl_xor(rm, 16));
      rm = fmaxf(rm, __shfl_xor(rm, 32));
      if (!__all(rm <= mrow[qs] + 8.f)) {     // defer-max (T13)
        float mn = fmaxf(mrow[qs], rm);
        float scl = exp2f(mrow[qs] - mn);
        mrow[qs] = mn;
        lsum[qs] *= scl;
        float c0 = __shfl(scl, hi * 4 + 0);
        float c1 = __shfl(scl, hi * 4 + 1);
        float c2 = __shfl(scl, hi * 4 + 2);
        float c3 = __shfl(scl, hi * 4 + 3);
#pragma unroll
        for (int tt = 0; tt < 4; tt++) {
          acc[qs][tt][0] *= c0; acc[qs][tt][1] *= c1;
          acc[qs][tt][2] *= c2; acc[qs][tt][3] *= c3;
        }
      }
      float m = mrow[qs];
      float rs = 0.f;
#pragma unroll
      for (int g = 0; g < 4; g++) {
        float p0 = exp2f(fmaf(ST[qs][g][0], SC2, -m));
        float p1 = exp2f(fmaf(ST[qs][g][1], SC2, -m));
        float p2 = exp2f(fmaf(ST[qs][g][2], SC2, -m));
        float p3 = exp2f(fmaf(ST[qs][g][3], SC2, -m));
        rs += (p0 + p1) + (p2 + p3);
        s16x4 pw;
        pw[0] = (short)f2us(p0); pw[1] = (short)f2us(p1);
        pw[2] = (short)f2us(p2); pw[3] = (short)f2us(p3);
        *(s16x4*)&P[(qs * 16 + lo) * 72 + g * 16 + hi * 4] = pw;
      }
      rs += __shfl_xor(rs, 16);
      rs += __shfl_xor(rs, 32);
      lsum[qs] += rs;
    }

    // PV from registers (vg waits resolved: loads issued last iteration)
    {
      bf16x8 pf[2][2];
#pragma unroll
      for (int qs = 0; qs < 2; qs++) {
        pf[qs][0] = *(const bf16x8*)&P[(qs * 16 + lo) * 72 + hi * 8];
        pf[qs][1] = *(const bf16x8*)&P[(qs * 16 + lo) * 72 + 32 + hi * 8];
      }
#pragma unroll
      for (int tt = 0; tt < 4; tt++)
#pragma unroll
        for (int qs = 0; qs < 2; qs++) {
          acc[qs][tt] = MFMA_BF16_16x16x32(pf[qs][0], vg[tt][0], acc[qs][tt], 0, 0, 0);
          acc[qs][tt] = MFMA_BF16_16x16x32(pf[qs][1], vg[tt][1], acc[qs][tt], 0, 0, 0);
        }
    }
    if (it + 1 < nt) loadV(it + 1);      // WAR on vg — lands during next QK^T+smax
  }

#pragma unroll
  for (int qs = 0; qs < 2; qs++) {
    float inv = 1.f / lsum[qs];
    float iv0 = __shfl(inv, hi * 4 + 0);
    float iv1 = __shfl(inv, hi * 4 + 1);
    float iv2 = __shfl(inv, hi * 4 + 2);
    float iv3 = __shfl(inv, hi * 4 + 3);
    float iv[4] = {iv0, iv1, iv2, iv3};
#pragma unroll
    for (int i = 0; i < 4; i++) {
      long row = q0 + qs * 16 + hi * 4 + i;
      __hip_bfloat16* op = out + ((long)b * Nq + row) * 1024 + h * 64 + lo;
#pragma unroll
      for (int tt = 0; tt < 4; tt++) op[tt * 16] = __float2bfloat16(acc[qs][tt][i] * iv[i]);
    }
  }
}

// ------------------------------ launch -------------------------------------

extern "C" void kernel_launch(void* const* d_in, const int* in_sizes, int n_in,
                              void* d_out, int out_size, void* d_ws, size_t ws_size,
                              hipStream_t stream) {
  (void)in_sizes; (void)n_in; (void)out_size; (void)ws_size;

  const float* x      = (const float*)d_in[0];
  const float* ctx    = (const float*)d_in[1];
  const float* rope   = (const float*)d_in[2];
  const float* wqkv   = (const float*)d_in[3];
  const float* sa_qg  = (const float*)d_in[4];
  const float* sa_qb  = (const float*)d_in[5];
  const float* sa_kg  = (const float*)d_in[6];
  const float* sa_kb  = (const float*)d_in[7];
  const float* sa_wo  = (const float*)d_in[8];
  const float* sa_bo  = (const float*)d_in[9];
  const float* ca_wq  = (const float*)d_in[10];
  const float* ca_wk  = (const float*)d_in[11];
  const float* ca_wv  = (const float*)d_in[12];
  const float* ca_qg  = (const float*)d_in[13];
  const float* ca_qb  = (const float*)d_in[14];
  const float* ca_kg  = (const float*)d_in[15];
  const float* ca_kb  = (const float*)d_in[16];
  const float* ca_wo  = (const float*)d_in[17];
  const float* ca_bo  = (const float*)d_in[18];
  const float* ca_gate= (const float*)d_in[19];
  const float* w1g    = (const float*)d_in[20];
  const float* b1g    = (const float*)d_in[21];
  const float* w1x    = (const float*)d_in[22];
  const float* b1x    = (const float*)d_in[23];
  const float* w2     = (const float*)d_in[24];
  const float* b2     = (const float*)d_in[25];
  const float* ls0    = (const float*)d_in[26];
  const float* ls1    = (const float*)d_in[27];
  const float* ls2    = (const float*)d_in[28];

  char* ws = (char*)d_ws;

  // workspace layout (bytes); peak 218,103,808 (208 MiB), manual reuse
  const long OFF_WQKVT = 0;
  const long OFF_SAWOT = 6291456;
  const long OFF_CAWQT = 8388608;
  const long OFF_CAWKT = 10485760;
  const long OFF_CAWVT = 12582912;
  const long OFF_CAWOT = 14680064;
  const long OFF_W1GT  = 16777216;
  const long OFF_W1XT  = 25165824;
  const long OFF_W2T   = 33554432;
  const long OFF_XB    = 41943040;   // 16 MB (dead after qkv gemm)
  const long OFF_QC    = OFF_XB;     //   reuse
  const long OFF_CTXB  = 58720256;
  const long OFF_QKV   = 67108864;   // 48 MB (dead after SA attn)
  const long OFF_CAO   = 67108864;
  const long OFF_X2B   = 83886080;
  const long OFF_SG    = 100663296;  // 64 MB (first written at MLP)
  const long OFF_SAO   = 117440512;
  const long OFF_KC    = 117440512;
  const long OFF_VC    = 125829120;
  const long OFF_X1    = 134217728;
  const long OFF_X1B   = 167772160;  // 16 MB (dead after ca_wq gemm)
  const long OFF_CAVT  = OFF_X1B;    //   reuse: CA V^T tiled (9,437,184)
  const long OFF_X2    = 184549376;  // 33.5 MB (written at step 13)
  const long OFF_SAVT  = OFF_X2;     //   reuse: SA V^T tiled (18,874,368), dead after SA attn

  auto bfp = [&](long off) { return (__hip_bfloat16*)(ws + off); };
  auto ffp = [&](long off) { return (float*)(ws + off); };

  dim3 tb32(32, 8);
  // 1. weight transposes
  transpose_cvt<<<dim3(96, 32), tb32, 0, stream>>>(wqkv,  bfp(OFF_WQKVT), 1024, 3072);
  transpose_cvt<<<dim3(32, 32), tb32, 0, stream>>>(sa_wo, bfp(OFF_SAWOT), 1024, 1024);
  transpose_cvt<<<dim3(32, 32), tb32, 0, stream>>>(ca_wq, bfp(OFF_CAWQT), 1024, 1024);
  transpose_cvt<<<dim3(32, 32), tb32, 0, stream>>>(ca_wk, bfp(OFF_CAWKT), 1024, 1024);
  transpose_cvt<<<dim3(32, 32), tb32, 0, stream>>>(ca_wv, bfp(OFF_CAWVT), 1024, 1024);
  transpose_cvt<<<dim3(32, 32), tb32, 0, stream>>>(ca_wo, bfp(OFF_CAWOT), 1024, 1024);
  transpose_cvt<<<dim3(128, 32), tb32, 0, stream>>>(w1g,  bfp(OFF_W1GT), 1024, 4096);
  transpose_cvt<<<dim3(128, 32), tb32, 0, stream>>>(w1x,  bfp(OFF_W1XT), 1024, 4096);
  transpose_cvt<<<dim3(32, 128), tb32, 0, stream>>>(w2,   bfp(OFF_W2T), 4096, 1024);

  // 2. activations -> bf16
  cvt_f32_bf16<<<8192, 256, 0, stream>>>(x,   bfp(OFF_XB),   8388608);
  cvt_f32_bf16<<<4096, 256, 0, stream>>>(ctx, bfp(OFF_CTXB), 4194304);

  // 3. qkv = xb @ wqkvT   (8192 x 3072 x 1024)
  gemm2ph<256, 0><<<dim3(32, 12), 512, 0, stream>>>(bfp(OFF_XB), bfp(OFF_WQKVT), 8192, 3072, 1024,
                                                    nullptr, bfp(OFF_QKV), nullptr, nullptr, nullptr, nullptr, nullptr);

  // 3b. SA V^T (tiled+padded; X2 region free until step 13)
  transpose_v<<<dim3(64, 2, 64), tb32, 0, stream>>>(bfp(OFF_QKV) + 2048, (long)2048 * 3072, 3072,
                                                    bfp(OFF_SAVT), 2048);

  // 4. SA LN + rope on q,k (in place in qkv)
  ln_rope<<<65536, 256, 0, stream>>>(bfp(OFF_QKV), rope, sa_qg, sa_qb, sa_kg, sa_kb,
                                     2048, 2, 3 * 1024, 1024, 3, (long)4 * 2048 * 16 * 2);

  // 5. self-attention
  attn32<<<1024, 256, 0, stream>>>(bfp(OFF_QKV),        (long)2048 * 3072, 3072,
                                   bfp(OFF_QKV) + 1024, (long)2048 * 3072, 3072,
                                   bfp(OFF_SAVT), bfp(OFF_SAO), 2048, 2048);

  // 6. sa proj + residual: x1 = ls0*(sa@wo + bo) + x   (8192 x 1024 x 1024)
  gemm2ph<128, 1><<<dim3(64, 4), 512, 0, stream>>>(bfp(OFF_SAO), bfp(OFF_SAWOT), 8192, 1024, 1024,
                                                   ffp(OFF_X1), bfp(OFF_X1B), sa_bo, ls0, nullptr, x, nullptr);

  // 7-9. CA projections
  gemm2ph<128, 0><<<dim3(64, 4), 512, 0, stream>>>(bfp(OFF_X1B), bfp(OFF_CAWQT), 8192, 1024, 1024,
                                                   nullptr, bfp(OFF_QC), nullptr, nullptr, nullptr, nullptr, nullptr);
  gemm128<0><<<dim3(32, 8), 256, 0, stream>>>(bfp(OFF_CTXB), bfp(OFF_CAWKT), 4096, 1024, 1024,
                                              nullptr, bfp(OFF_KC), nullptr, nullptr, nullptr, nullptr, nullptr);
  gemm128<0><<<dim3(32, 8), 256, 0, stream>>>(bfp(OFF_CTXB), bfp(OFF_CAWVT), 4096, 1024, 1024,
                                              nullptr, bfp(OFF_VC), nullptr, nullptr, nullptr, nullptr, nullptr);

  // 9b. CA V^T (tiled+padded; X1B dead after ca_wq gemm)
  transpose_v<<<dim3(32, 2, 64), tb32, 0, stream>>>(bfp(OFF_VC), (long)1024 * 1024, 1024,
                                                    bfp(OFF_CAVT), 1024);

  // 10-11. CA LN (+rope on q only)
  ln_rope<<<32768, 256, 0, stream>>>(bfp(OFF_QC), rope, ca_qg, ca_qb, ca_qg, ca_qb,
                                     2048, 1, 1024, 0, 1, (long)4 * 2048 * 16);
  ln_rope<<<16384, 256, 0, stream>>>(bfp(OFF_KC), rope, ca_kg, ca_kb, ca_kg, ca_kb,
                                     1024, 1, 1024, 0, 0, (long)4 * 1024 * 16);

  // 12. cross-attention
  attn32<<<1024, 256, 0, stream>>>(bfp(OFF_QC), (long)2048 * 1024, 1024,
                                   bfp(OFF_KC), (long)1024 * 1024, 1024,
                                   bfp(OFF_CAVT), bfp(OFF_CAO), 2048, 1024);

  // 13. ca proj: x2 = ls1*((ca@wo + bo)*tanh(gate)) + x1
  gemm2ph<128, 2><<<dim3(64, 4), 512, 0, stream>>>(bfp(OFF_CAO), bfp(OFF_CAWOT), 8192, 1024, 1024,
                                                   ffp(OFF_X2), bfp(OFF_X2B), ca_bo, ls1, ca_gate, ffp(OFF_X1), nullptr);

  // 14. sg = silu(x2b @ w1gT + b1g)   (8192 x 4096 x 1024)
  gemm2ph<256, 3><<<dim3(32, 16), 512, 0, stream>>>(bfp(OFF_X2B), bfp(OFF_W1GT), 8192, 4096, 1024,
                                                    nullptr, bfp(OFF_SG), b1g, nullptr, nullptr, nullptr, nullptr);
  // 15. sg *= (x2b @ w1xT + b1x)
  gemm2ph<256, 4><<<dim3(32, 16), 512, 0, stream>>>(bfp(OFF_X2B), bfp(OFF_W1XT), 8192, 4096, 1024,
                                                    nullptr, bfp(OFF_SG), b1x, nullptr, nullptr, nullptr, bfp(OFF_SG));
  // 16. out = ls2*(sg @ w2T + b2) + x2   (8192 x 1024 x 4096)
  gemm2ph<128, 5><<<dim3(64, 4), 512, 0, stream>>>(bfp(OFF_SG), bfp(OFF_W2T), 8192, 1024, 4096,
                                                   (float*)d_out, nullptr, b2, ls2, nullptr, ffp(OFF_X2), nullptr);
}

// Round 13
// 996.812 us; speedup vs baseline: 1.0683x; 1.0683x over previous
//
#include <hip/hip_runtime.h>
#include <hip/hip_bf16.h>
#include <math.h>

// ---------------------------------------------------------------------------
// CrossAttentionBlock on MI355X (gfx950) — round 12: revert to the measured-
// best 907µs configuration (r5 BK=64 2-phase GEMM + r7 attention with K
// reg-dbuf and shared V LDS staging; r11's barrier-free attn spilled to
// scratch and regressed). One new lever: T1 XCD-aware chunked blockIdx
// swizzle on gemm2ph (bijective — all grids % 8 == 0) for B-panel L2 reuse.
// B=4 N=2048 M=1024 C=1024 H=16 HD=64 HID=4096
// ---------------------------------------------------------------------------

typedef __attribute__((ext_vector_type(8))) short bf16x8;   // 8 bf16 in 4 VGPRs
typedef __attribute__((ext_vector_type(4))) short s16x4;    // 4 bf16 (8B)
typedef __attribute__((ext_vector_type(4))) float f32x4;

#define DEV __device__ __forceinline__

DEV unsigned short f2us(float f) {
  __hip_bfloat16 h = __float2bfloat16(f);
  return __builtin_bit_cast(unsigned short, h);
}

DEV void gload_lds16(const void* g, void* l) {
  __builtin_amdgcn_global_load_lds((const __attribute__((address_space(1))) void*)g,
                                   (__attribute__((address_space(3))) void*)l, 16, 0, 0);
}

#define MFMA_BF16_16x16x32 __builtin_amdgcn_mfma_f32_16x16x32_bf16
#define WAITV0 asm volatile("s_waitcnt vmcnt(0)" ::: "memory")

// ------------------------- elementwise converts ----------------------------

__global__ __launch_bounds__(256) void cvt_f32_bf16(const float* __restrict__ in,
                                                    __hip_bfloat16* __restrict__ out,
                                                    long n) {
  long i = ((long)blockIdx.x * blockDim.x + threadIdx.x) * 4;
  if (i + 3 < n) {
    float4 v = *(const float4*)(in + i);
    out[i + 0] = __float2bfloat16(v.x);
    out[i + 1] = __float2bfloat16(v.y);
    out[i + 2] = __float2bfloat16(v.z);
    out[i + 3] = __float2bfloat16(v.w);
  }
}

// w (K,N) fp32 row-major -> wT (N,K) bf16 row-major
__global__ __launch_bounds__(256) void transpose_cvt(const float* __restrict__ w,
                                                     __hip_bfloat16* __restrict__ wT,
                                                     int K, int N) {
  __shared__ float tile[32][33];
  int n0 = blockIdx.x * 32, k0 = blockIdx.y * 32;
  int tx = threadIdx.x, ty = threadIdx.y;
  #pragma unroll
  for (int i = 0; i < 32; i += 8)
    tile[ty + i][tx] = w[(long)(k0 + ty + i) * N + n0 + tx];
  __syncthreads();
  #pragma unroll
  for (int i = 0; i < 32; i += 8)
    wT[(long)(n0 + ty + i) * K + k0 + tx] = __float2bfloat16(tile[tx][ty + i]);
}

// V (strided, bf16) -> V^T tiled [bh][Nkv/64][64 d][72 kv(padded)] (bf16)
__global__ __launch_bounds__(256) void transpose_v(const __hip_bfloat16* __restrict__ v,
                                                   long vBatch, long vRow,
                                                   __hip_bfloat16* __restrict__ vt,
                                                   int Nkv) {
  __shared__ unsigned short tile[32][36];
  int bh = blockIdx.z;
  int b = bh >> 4, h = bh & 15;
  int kv0 = blockIdx.x * 32;
  int d0 = blockIdx.y * 32;
  int tx = threadIdx.x, ty = threadIdx.y;   // (32,8)
  const __hip_bfloat16* src = v + (long)b * vBatch + h * 64 + d0;
  #pragma unroll
  for (int i = 0; i < 32; i += 8)
    tile[ty + i][tx] = __builtin_bit_cast(unsigned short, src[(long)(kv0 + ty + i) * vRow + tx]);
  __syncthreads();
  unsigned short* dst = (unsigned short*)vt + ((long)bh * (Nkv >> 6) + (kv0 >> 6)) * 4608 + (kv0 & 32) + tx;
  #pragma unroll
  for (int i = 0; i < 32; i += 8)
    dst[(long)(d0 + ty + i) * 72] = tile[tx][ty + i];
}

// ------------------------------ LN + RoPE ----------------------------------
__global__ __launch_bounds__(256) void ln_rope(__hip_bfloat16* __restrict__ buf,
                                               const float* __restrict__ rope,
                                               const float* __restrict__ g0,
                                               const float* __restrict__ b0,
                                               const float* __restrict__ g1,
                                               const float* __restrict__ b1,
                                               int Rows, int W,
                                               long rowStride, long whichStride,
                                               int ropeMask, long total) {
  int lane = threadIdx.x & 63;
  int wv = threadIdx.x >> 6;
  long id = (long)blockIdx.x * 4 + wv;
  if (id >= total) return;
  int which = (int)(id % W);
  long t = id / W;
  int h = (int)(t & 15); t >>= 4;
  int n = (int)(t % Rows);
  int b = (int)(t / Rows);
  __hip_bfloat16* p = buf + ((long)b * Rows + n) * rowStride + (long)which * whichStride + h * 64 + lane;
  float v = __bfloat162float(*p);
  float s = v;
  #pragma unroll
  for (int m = 32; m; m >>= 1) s += __shfl_xor(s, m);
  float mean = s * (1.f / 64.f);
  float d = v - mean;
  float q = d * d;
  #pragma unroll
  for (int m = 32; m; m >>= 1) q += __shfl_xor(q, m);
  float rstd = rsqrtf(q * (1.f / 64.f) + 1e-6f);
  const float* g = which ? g1 : g0;
  const float* bb = which ? b1 : b0;
  float xn = d * rstd * g[lane] + bb[lane];
  if ((ropeMask >> which) & 1) {
    float partner = __shfl_xor(xn, 1);
    float sn = rope[(long)n * 128 + lane];
    float cs = rope[(long)n * 128 + 64 + lane];
    xn = (lane & 1) ? (xn * cs + partner * sn) : (xn * cs - partner * sn);
  }
  *p = __float2bfloat16(xn);
}

// --------------------- epilogue helper (shared by GEMMs) -------------------
template <int EPI>
DEV void epi_store(long idx, long col, float v,
                   float* __restrict__ out_f, __hip_bfloat16* __restrict__ out_b,
                   const float* __restrict__ bias, const float* __restrict__ scale,
                   const float* __restrict__ gate, const float* __restrict__ resid,
                   const __hip_bfloat16* __restrict__ mulin) {
  if constexpr (EPI == 0) {
    out_b[idx] = __float2bfloat16(v);
  } else if constexpr (EPI == 1) {
    float r = scale[col] * (v + bias[col]) + resid[idx];
    out_f[idx] = r;
    out_b[idx] = __float2bfloat16(r);
  } else if constexpr (EPI == 2) {
    float r = scale[col] * ((v + bias[col]) * tanhf(gate[col])) + resid[idx];
    out_f[idx] = r;
    out_b[idx] = __float2bfloat16(r);
  } else if constexpr (EPI == 3) {
    float z = v + bias[col];
    out_b[idx] = __float2bfloat16(z / (1.f + expf(-z)));
  } else if constexpr (EPI == 4) {
    float z = (v + bias[col]) * __bfloat162float(mulin[idx]);
    out_b[idx] = __float2bfloat16(z);
  } else {
    out_f[idx] = scale[col] * (v + bias[col]) + resid[idx];
  }
}

// ------------------------------ GEMM 128² (legacy, small shapes) -----------
template <int EPI>
__global__ __launch_bounds__(256) void gemm128(const __hip_bfloat16* __restrict__ A,
                                               const __hip_bfloat16* __restrict__ Bt,
                                               int M, int N, int K,
                                               float* __restrict__ out_f,
                                               __hip_bfloat16* __restrict__ out_b,
                                               const float* __restrict__ bias,
                                               const float* __restrict__ scale,
                                               const float* __restrict__ gate,
                                               const float* __restrict__ resid,
                                               const __hip_bfloat16* __restrict__ mulin) {
  __shared__ unsigned short As[128 * 32];
  __shared__ unsigned short Bs[128 * 32];
  int t = threadIdx.x;
  int l = t & 63;
  int w = t >> 6;
  int wr = w >> 1, wc = w & 1;
  long bm = blockIdx.x, bn = blockIdx.y;
  const __hip_bfloat16* Ab = A + bm * 128 * (long)K;
  const __hip_bfloat16* Bb = Bt + bn * 128 * (long)K;

  f32x4 acc[4][4] = {};

  for (int k0 = 0; k0 < K; k0 += 32) {
    #pragma unroll
    for (int j = 0; j < 2; j++) {
      int c = j * 256 + t;
      int row = c >> 2;
      int ko = (c & 3) * 8;
      gload_lds16(Ab + (long)row * K + k0 + ko, &As[c * 8]);
      gload_lds16(Bb + (long)row * K + k0 + ko, &Bs[c * 8]);
    }
    __syncthreads();
    bf16x8 af[4], bfg[4];
    #pragma unroll
    for (int m = 0; m < 4; m++)
      af[m] = *(const bf16x8*)&As[(wr * 64 + m * 16 + (l & 15)) * 32 + (l >> 4) * 8];
    #pragma unroll
    for (int n = 0; n < 4; n++)
      bfg[n] = *(const bf16x8*)&Bs[(wc * 64 + n * 16 + (l & 15)) * 32 + (l >> 4) * 8];
    #pragma unroll
    for (int m = 0; m < 4; m++)
      #pragma unroll
      for (int n = 0; n < 4; n++)
        acc[m][n] = MFMA_BF16_16x16x32(af[m], bfg[n], acc[m][n], 0, 0, 0);
    __syncthreads();
  }

  #pragma unroll
  for (int m = 0; m < 4; m++)
    #pragma unroll
    for (int n = 0; n < 4; n++)
      #pragma unroll
      for (int i = 0; i < 4; i++) {
        long row = bm * 128 + wr * 64 + m * 16 + (l >> 4) * 4 + i;
        long col = bn * 128 + wc * 64 + n * 16 + (l & 15);
        epi_store<EPI>(row * (long)N + col, col, acc[m][n][i],
                       out_f, out_b, bias, scale, gate, resid, mulin);
      }
}

// --------------- GEMM BMx256, BK=64, 2-phase (T3 minimum, r5) --------------
// + T1 XCD-aware chunked blockIdx swizzle (grids % 8 == 0 -> bijective).
// 512 threads = 8 waves (2 M x 4 N). Double-buffered LDS; per K-tile:
// {stage(t+1) -> ds_read frags -> setprio MFMA -> vmcnt(0) -> s_barrier}.
// 3-bit chunk swizzle (c ^= row&7) on BOTH gload source and ds_read address.
template <int BM, int EPI>
__global__ __launch_bounds__(512, 2) void gemm2ph(const __hip_bfloat16* __restrict__ A,
                                                  const __hip_bfloat16* __restrict__ Bt,
                                                  int M, int N, int K,
                                                  float* __restrict__ out_f,
                                                  __hip_bfloat16* __restrict__ out_b,
                                                  const float* __restrict__ bias,
                                                  const float* __restrict__ scale,
                                                  const float* __restrict__ gate,
                                                  const float* __restrict__ resid,
                                                  const __hip_bfloat16* __restrict__ mulin) {
  constexpr int MF = BM / 32;          // m-frags per wave (8 or 4)
  constexpr int WRS = BM / 2;          // wave row span
  constexpr int AJ = BM * 8 / 512;     // A chunks per thread (4 or 2)
  __shared__ __align__(16) unsigned short As[2][BM * 64];
  __shared__ __align__(16) unsigned short Bs[2][256 * 64];

  int t = threadIdx.x;
  int l = t & 63, w = t >> 6;
  int lo = l & 15, hi = l >> 4;
  int wr = w >> 2, wc = w & 3;         // 2 x 4 waves

  // T1: XCD-aware chunked remap (HW: wg % 8 = XCD). nwg % 8 == 0 for all
  // call sites (384, 256, 512) -> bijective.
  int nwgx = gridDim.x;
  int nwg = nwgx * gridDim.y;
  int wg = blockIdx.y * nwgx + blockIdx.x;
  int cpx = nwg >> 3;
  int swz = (wg & 7) * cpx + (wg >> 3);
  long bm = swz % nwgx, bn = swz / nwgx;

  const __hip_bfloat16* Ab = A + bm * BM * (long)K;
  const __hip_bfloat16* Bb = Bt + bn * 256 * (long)K;
  int nt = K >> 6;

  auto stage = [&](int kt, int buf) {
    long kb = (long)kt * 64;
    #pragma unroll
    for (int j = 0; j < AJ; j++) {
      int q = j * 512 + t;
      int row = q >> 3, c = (q & 7) ^ (row & 7);
      gload_lds16(Ab + (long)row * K + kb + c * 8, &As[buf][q * 8]);
    }
    #pragma unroll
    for (int j = 0; j < 4; j++) {
      int q = j * 512 + t;
      int row = q >> 3, c = (q & 7) ^ (row & 7);
      gload_lds16(Bb + (long)row * K + kb + c * 8, &Bs[buf][q * 8]);
    }
  };

  f32x4 acc[MF][4] = {};

  stage(0, 0);
  WAITV0;
  __builtin_amdgcn_s_barrier();

  for (int kt = 0; kt < nt; ++kt) {
    int cur = kt & 1;
    if (kt + 1 < nt) stage(kt + 1, cur ^ 1);

    #pragma unroll
    for (int ks = 0; ks < 2; ks++) {
      bf16x8 bfrag[4];
      #pragma unroll
      for (int n = 0; n < 4; n++) {
        int rb = wc * 64 + n * 16 + lo;
        bfrag[n] = *(const bf16x8*)&Bs[cur][rb * 64 + (((ks << 2) | hi) ^ (rb & 7)) * 8];
      }
      #pragma unroll
      for (int mg = 0; mg < MF; mg += 4) {
        bf16x8 afrag[4];
        #pragma unroll
        for (int m = 0; m < 4; m++) {
          int ra = wr * WRS + (mg + m) * 16 + lo;
          afrag[m] = *(const bf16x8*)&As[cur][ra * 64 + (((ks << 2) | hi) ^ (ra & 7)) * 8];
        }
        __builtin_amdgcn_s_setprio(1);
        #pragma unroll
        for (int m = 0; m < 4; m++)
          #pragma unroll
          for (int n = 0; n < 4; n++)
            acc[mg + m][n] = MFMA_BF16_16x16x32(afrag[m], bfrag[n], acc[mg + m][n], 0, 0, 0);
        __builtin_amdgcn_s_setprio(0);
      }
    }

    if (kt + 1 < nt) {
      WAITV0;                          // next tile fully in LDS (issued early)
      __builtin_amdgcn_s_barrier();    // all waves' reads of cur done too
    }
  }

  #pragma unroll
  for (int m = 0; m < MF; m++)
    #pragma unroll
    for (int n = 0; n < 4; n++)
      #pragma unroll
      for (int i = 0; i < 4; i++) {
        long row = bm * BM + wr * WRS + m * 16 + hi * 4 + i;
        long col = bn * 256 + wc * 64 + n * 16 + lo;
        epi_store<EPI>(row * (long)N + col, col, acc[m][n][i],
                       out_f, out_b, bias, scale, gate, resid, mulin);
      }
}

// ---------------------------- attention ------------------------------------
// r7 version (measured 184 µs SA): 4 waves/block, 32 q-rows/wave, KVBLK=64,
// swapped QK^T, defer-max, V^T LDS dbuf, K register double-buffer with NAMED
// kgA/kgB and 2-tile unrolled loop (K(t+1) issued before softmax/PV of t).
__global__ __launch_bounds__(256) void attn32(const __hip_bfloat16* __restrict__ qB, long qBatch, long qRow,
                                              const __hip_bfloat16* __restrict__ kB, long kBatch, long kRow,
                                              const __hip_bfloat16* __restrict__ vt,
                                              __hip_bfloat16* __restrict__ out, int Nq, int Nkv) {
  const float SC2 = 0.125f * 1.44269504089f;   // scale * log2(e)
  int t = threadIdx.x;
  int l = t & 63, w = t >> 6;
  int lo = l & 15, hi = l >> 4;
  int nQC = Nq >> 7;
  int qc = blockIdx.x % nQC;
  int bh = blockIdx.x / nQC;
  int h = bh & 15, b = bh >> 4;
  int q0 = qc * 128 + w * 32;

  __shared__ unsigned short P_all[4][32 * 72];
  __shared__ unsigned short V_lds[2][64 * 72];
  unsigned short* P = P_all[w];

  bf16x8 qf[2][2];
#pragma unroll
  for (int qs = 0; qs < 2; qs++) {
    const __hip_bfloat16* qp = qB + (long)b * qBatch + (long)(q0 + qs * 16 + lo) * qRow + h * 64 + hi * 8;
    qf[qs][0] = *(const bf16x8*)qp;
    qf[qs][1] = *(const bf16x8*)(qp + 32);
  }

  float mrow[2] = {-INFINITY, -INFINITY};
  float lsum[2] = {0.f, 0.f};
  f32x4 acc[2][4] = {};
  const f32x4 fz = {0.f, 0.f, 0.f, 0.f};

  const __hip_bfloat16* kbase = kB + (long)b * kBatch + h * 64 + hi * 8;
  int nt = Nkv >> 6;   // even (32 or 16)
  const char* vtb = (const char*)vt + (long)bh * nt * 9216;

  auto stageV = [&](int tile, unsigned short* dstb) {
    const char* src = vtb + (long)tile * 9216;
    gload_lds16(src + t * 16, &dstb[t * 8]);
    gload_lds16(src + (t + 256) * 16, &dstb[(t + 256) * 8]);
    if (t < 64) gload_lds16(src + (t + 512) * 16, &dstb[(t + 512) * 8]);
  };
  auto loadK = [&](int tile, bf16x8 (&kg)[4][2]) {
#pragma unroll
    for (int g = 0; g < 4; g++) {
      const __hip_bfloat16* kp = kbase + (long)(tile * 64 + g * 16 + lo) * kRow;
      kg[g][0] = *(const bf16x8*)kp;
      kg[g][1] = *(const bf16x8*)(kp + 32);
    }
  };
  auto qkt = [&](bf16x8 (&kg)[4][2], f32x4 (&ST)[2][4]) {
#pragma unroll
    for (int qs = 0; qs < 2; qs++)
#pragma unroll
      for (int g = 0; g < 4; g++) {
        f32x4 s0 = MFMA_BF16_16x16x32(kg[g][0], qf[qs][0], fz, 0, 0, 0);
        ST[qs][g] = MFMA_BF16_16x16x32(kg[g][1], qf[qs][1], s0, 0, 0, 0);
      }
  };
  auto smax = [&](f32x4 (&ST)[2][4]) {
#pragma unroll
    for (int qs = 0; qs < 2; qs++) {
      float mg0 = fmaxf(fmaxf(ST[qs][0][0], ST[qs][0][1]), fmaxf(ST[qs][0][2], ST[qs][0][3]));
      float mg1 = fmaxf(fmaxf(ST[qs][1][0], ST[qs][1][1]), fmaxf(ST[qs][1][2], ST[qs][1][3]));
      float mg2 = fmaxf(fmaxf(ST[qs][2][0], ST[qs][2][1]), fmaxf(ST[qs][2][2], ST[qs][2][3]));
      float mg3 = fmaxf(fmaxf(ST[qs][3][0], ST[qs][3][1]), fmaxf(ST[qs][3][2], ST[qs][3][3]));
      float rm = fmaxf(fmaxf(mg0, mg1), fmaxf(mg2, mg3)) * SC2;
      rm = fmaxf(rm, __shfl_xor(rm, 16));
      rm = fmaxf(rm, __shfl_xor(rm, 32));
      if (!__all(rm <= mrow[qs] + 8.f)) {     // defer-max (T13)
        float mn = fmaxf(mrow[qs], rm);
        float scl = exp2f(mrow[qs] - mn);
        mrow[qs] = mn;
        lsum[qs] *= scl;
        float c0 = __shfl(scl, hi * 4 + 0);
        float c1 = __shfl(scl, hi * 4 + 1);
        float c2 = __shfl(scl, hi * 4 + 2);
        float c3 = __shfl(scl, hi * 4 + 3);
#pragma unroll
        for (int tt = 0; tt < 4; tt++) {
          acc[qs][tt][0] *= c0; acc[qs][tt][1] *= c1;
          acc[qs][tt][2] *= c2; acc[qs][tt][3] *= c3;
        }
      }
      float m = mrow[qs];
      float rs = 0.f;
#pragma unroll
      for (int g = 0; g < 4; g++) {
        float p0 = exp2f(fmaf(ST[qs][g][0], SC2, -m));
        float p1 = exp2f(fmaf(ST[qs][g][1], SC2, -m));
        float p2 = exp2f(fmaf(ST[qs][g][2], SC2, -m));
        float p3 = exp2f(fmaf(ST[qs][g][3], SC2, -m));
        rs += (p0 + p1) + (p2 + p3);
        s16x4 pw;
        pw[0] = (short)f2us(p0); pw[1] = (short)f2us(p1);
        pw[2] = (short)f2us(p2); pw[3] = (short)f2us(p3);
        *(s16x4*)&P[(qs * 16 + lo) * 72 + g * 16 + hi * 4] = pw;
      }
      rs += __shfl_xor(rs, 16);
      rs += __shfl_xor(rs, 32);
      lsum[qs] += rs;
    }
  };
  auto pv = [&](const unsigned short* Vb) {
    bf16x8 pf[2][2];
#pragma unroll
    for (int qs = 0; qs < 2; qs++) {
      pf[qs][0] = *(const bf16x8*)&P[(qs * 16 + lo) * 72 + hi * 8];
      pf[qs][1] = *(const bf16x8*)&P[(qs * 16 + lo) * 72 + 32 + hi * 8];
    }
#pragma unroll
    for (int tt = 0; tt < 4; tt++) {
      bf16x8 v0 = *(const bf16x8*)&Vb[(tt * 16 + lo) * 72 + hi * 8];
      bf16x8 v1 = *(const bf16x8*)&Vb[(tt * 16 + lo) * 72 + 32 + hi * 8];
#pragma unroll
      for (int qs = 0; qs < 2; qs++) {
        acc[qs][tt] = MFMA_BF16_16x16x32(pf[qs][0], v0, acc[qs][tt], 0, 0, 0);
        acc[qs][tt] = MFMA_BF16_16x16x32(pf[qs][1], v1, acc[qs][tt], 0, 0, 0);
      }
    }
  };

  // prologue: V tile 0 -> buf0; K tile 0 -> kgA
  bf16x8 kgA[4][2], kgB[4][2];
  stageV(0, V_lds[0]);
  loadK(0, kgA);

  for (int it = 0; it < nt; it += 2) {
    __syncthreads();                       // V[it]@buf0 + K[it] complete (vmcnt drain)
    stageV(it + 1, V_lds[1]);              // nt even -> it+1 < nt always
    f32x4 ST0[2][4];
    qkt(kgA, ST0);
    loadK(it + 1, kgB);                    // hide K latency under softmax+PV
    smax(ST0);
    pv(V_lds[0]);

    __syncthreads();                       // V[it+1]@buf1 + K[it+1] complete
    if (it + 2 < nt) stageV(it + 2, V_lds[0]);
    f32x4 ST1[2][4];
    qkt(kgB, ST1);
    if (it + 2 < nt) loadK(it + 2, kgA);
    smax(ST1);
    pv(V_lds[1]);
  }

#pragma unroll
  for (int qs = 0; qs < 2; qs++) {
    float inv = 1.f / lsum[qs];
    float iv0 = __shfl(inv, hi * 4 + 0);
    float iv1 = __shfl(inv, hi * 4 + 1);
    float iv2 = __shfl(inv, hi * 4 + 2);
    float iv3 = __shfl(inv, hi * 4 + 3);
    float iv[4] = {iv0, iv1, iv2, iv3};
#pragma unroll
    for (int i = 0; i < 4; i++) {
      long row = q0 + qs * 16 + hi * 4 + i;
      __hip_bfloat16* op = out + ((long)b * Nq + row) * 1024 + h * 64 + lo;
#pragma unroll
      for (int tt = 0; tt < 4; tt++) op[tt * 16] = __float2bfloat16(acc[qs][tt][i] * iv[i]);
    }
  }
}

// ------------------------------ launch -------------------------------------

extern "C" void kernel_launch(void* const* d_in, const int* in_sizes, int n_in,
                              void* d_out, int out_size, void* d_ws, size_t ws_size,
                              hipStream_t stream) {
  (void)in_sizes; (void)n_in; (void)out_size; (void)ws_size;

  const float* x      = (const float*)d_in[0];
  const float* ctx    = (const float*)d_in[1];
  const float* rope   = (const float*)d_in[2];
  const float* wqkv   = (const float*)d_in[3];
  const float* sa_qg  = (const float*)d_in[4];
  const float* sa_qb  = (const float*)d_in[5];
  const float* sa_kg  = (const float*)d_in[6];
  const float* sa_kb  = (const float*)d_in[7];
  const float* sa_wo  = (const float*)d_in[8];
  const float* sa_bo  = (const float*)d_in[9];
  const float* ca_wq  = (const float*)d_in[10];
  const float* ca_wk  = (const float*)d_in[11];
  const float* ca_wv  = (const float*)d_in[12];
  const float* ca_qg  = (const float*)d_in[13];
  const float* ca_qb  = (const float*)d_in[14];
  const float* ca_kg  = (const float*)d_in[15];
  const float* ca_kb  = (const float*)d_in[16];
  const float* ca_wo  = (const float*)d_in[17];
  const float* ca_bo  = (const float*)d_in[18];
  const float* ca_gate= (const float*)d_in[19];
  const float* w1g    = (const float*)d_in[20];
  const float* b1g    = (const float*)d_in[21];
  const float* w1x    = (const float*)d_in[22];
  const float* b1x    = (const float*)d_in[23];
  const float* w2     = (const float*)d_in[24];
  const float* b2     = (const float*)d_in[25];
  const float* ls0    = (const float*)d_in[26];
  const float* ls1    = (const float*)d_in[27];
  const float* ls2    = (const float*)d_in[28];

  char* ws = (char*)d_ws;

  // workspace layout (bytes); peak 218,103,808 (208 MiB), manual reuse
  const long OFF_WQKVT = 0;
  const long OFF_SAWOT = 6291456;
  const long OFF_CAWQT = 8388608;
  const long OFF_CAWKT = 10485760;
  const long OFF_CAWVT = 12582912;
  const long OFF_CAWOT = 14680064;
  const long OFF_W1GT  = 16777216;
  const long OFF_W1XT  = 25165824;
  const long OFF_W2T   = 33554432;
  const long OFF_XB    = 41943040;   // 16 MB (dead after qkv gemm)
  const long OFF_QC    = OFF_XB;     //   reuse
  const long OFF_CTXB  = 58720256;
  const long OFF_QKV   = 67108864;   // 48 MB (dead after SA attn)
  const long OFF_CAO   = 67108864;
  const long OFF_X2B   = 83886080;
  const long OFF_SG    = 100663296;  // 64 MB (first written at MLP)
  const long OFF_SAO   = 117440512;
  const long OFF_KC    = 117440512;
  const long OFF_VC    = 125829120;
  const long OFF_X1    = 134217728;
  const long OFF_X1B   = 167772160;  // 16 MB (dead after ca_wq gemm)
  const long OFF_CAVT  = OFF_X1B;    //   reuse: CA V^T tiled (9,437,184)
  const long OFF_X2    = 184549376;  // 33.5 MB (written at step 13)
  const long OFF_SAVT  = OFF_X2;     //   reuse: SA V^T tiled (18,874,368), dead after SA attn

  auto bfp = [&](long off) { return (__hip_bfloat16*)(ws + off); };
  auto ffp = [&](long off) { return (float*)(ws + off); };

  dim3 tb32(32, 8);
  // 1. weight transposes
  transpose_cvt<<<dim3(96, 32), tb32, 0, stream>>>(wqkv,  bfp(OFF_WQKVT), 1024, 3072);
  transpose_cvt<<<dim3(32, 32), tb32, 0, stream>>>(sa_wo, bfp(OFF_SAWOT), 1024, 1024);
  transpose_cvt<<<dim3(32, 32), tb32, 0, stream>>>(ca_wq, bfp(OFF_CAWQT), 1024, 1024);
  transpose_cvt<<<dim3(32, 32), tb32, 0, stream>>>(ca_wk, bfp(OFF_CAWKT), 1024, 1024);
  transpose_cvt<<<dim3(32, 32), tb32, 0, stream>>>(ca_wv, bfp(OFF_CAWVT), 1024, 1024);
  transpose_cvt<<<dim3(32, 32), tb32, 0, stream>>>(ca_wo, bfp(OFF_CAWOT), 1024, 1024);
  transpose_cvt<<<dim3(128, 32), tb32, 0, stream>>>(w1g,  bfp(OFF_W1GT), 1024, 4096);
  transpose_cvt<<<dim3(128, 32), tb32, 0, stream>>>(w1x,  bfp(OFF_W1XT), 1024, 4096);
  transpose_cvt<<<dim3(32, 128), tb32, 0, stream>>>(w2,   bfp(OFF_W2T), 4096, 1024);

  // 2. activations -> bf16
  cvt_f32_bf16<<<8192, 256, 0, stream>>>(x,   bfp(OFF_XB),   8388608);
  cvt_f32_bf16<<<4096, 256, 0, stream>>>(ctx, bfp(OFF_CTXB), 4194304);

  // 3. qkv = xb @ wqkvT   (8192 x 3072 x 1024)
  gemm2ph<256, 0><<<dim3(32, 12), 512, 0, stream>>>(bfp(OFF_XB), bfp(OFF_WQKVT), 8192, 3072, 1024,
                                                    nullptr, bfp(OFF_QKV), nullptr, nullptr, nullptr, nullptr, nullptr);

  // 3b. SA V^T (tiled+padded; X2 region free until step 13)
  transpose_v<<<dim3(64, 2, 64), tb32, 0, stream>>>(bfp(OFF_QKV) + 2048, (long)2048 * 3072, 3072,
                                                    bfp(OFF_SAVT), 2048);

  // 4. SA LN + rope on q,k (in place in qkv)
  ln_rope<<<65536, 256, 0, stream>>>(bfp(OFF_QKV), rope, sa_qg, sa_qb, sa_kg, sa_kb,
                                     2048, 2, 3 * 1024, 1024, 3, (long)4 * 2048 * 16 * 2);

  // 5. self-attention
  attn32<<<1024, 256, 0, stream>>>(bfp(OFF_QKV),        (long)2048 * 3072, 3072,
                                   bfp(OFF_QKV) + 1024, (long)2048 * 3072, 3072,
                                   bfp(OFF_SAVT), bfp(OFF_SAO), 2048, 2048);

  // 6. sa proj + residual: x1 = ls0*(sa@wo + bo) + x   (8192 x 1024 x 1024)
  gemm2ph<128, 1><<<dim3(64, 4), 512, 0, stream>>>(bfp(OFF_SAO), bfp(OFF_SAWOT), 8192, 1024, 1024,
                                                   ffp(OFF_X1), bfp(OFF_X1B), sa_bo, ls0, nullptr, x, nullptr);

  // 7-9. CA projections
  gemm2ph<128, 0><<<dim3(64, 4), 512, 0, stream>>>(bfp(OFF_X1B), bfp(OFF_CAWQT), 8192, 1024, 1024,
                                                   nullptr, bfp(OFF_QC), nullptr, nullptr, nullptr, nullptr, nullptr);
  gemm128<0><<<dim3(32, 8), 256, 0, stream>>>(bfp(OFF_CTXB), bfp(OFF_CAWKT), 4096, 1024, 1024,
                                              nullptr, bfp(OFF_KC), nullptr, nullptr, nullptr, nullptr, nullptr);
  gemm128<0><<<dim3(32, 8), 256, 0, stream>>>(bfp(OFF_CTXB), bfp(OFF_CAWVT), 4096, 1024, 1024,
                                              nullptr, bfp(OFF_VC), nullptr, nullptr, nullptr, nullptr, nullptr);

  // 9b. CA V^T (tiled+padded; X1B dead after ca_wq gemm)
  transpose_v<<<dim3(32, 2, 64), tb32, 0, stream>>>(bfp(OFF_VC), (long)1024 * 1024, 1024,
                                                    bfp(OFF_CAVT), 1024);

  // 10-11. CA LN (+rope on q only)
  ln_rope<<<32768, 256, 0, stream>>>(bfp(OFF_QC), rope, ca_qg, ca_qb, ca_qg, ca_qb,
                                     2048, 1, 1024, 0, 1, (long)4 * 2048 * 16);
  ln_rope<<<16384, 256, 0, stream>>>(bfp(OFF_KC), rope, ca_kg, ca_kb, ca_kg, ca_kb,
                                     1024, 1, 1024, 0, 0, (long)4 * 1024 * 16);

  // 12. cross-attention
  attn32<<<1024, 256, 0, stream>>>(bfp(OFF_QC), (long)2048 * 1024, 1024,
                                   bfp(OFF_KC), (long)1024 * 1024, 1024,
                                   bfp(OFF_CAVT), bfp(OFF_CAO), 2048, 1024);

  // 13. ca proj: x2 = ls1*((ca@wo + bo)*tanh(gate)) + x1
  gemm2ph<128, 2><<<dim3(64, 4), 512, 0, stream>>>(bfp(OFF_CAO), bfp(OFF_CAWOT), 8192, 1024, 1024,
                                                   ffp(OFF_X2), bfp(OFF_X2B), ca_bo, ls1, ca_gate, ffp(OFF_X1), nullptr);

  // 14. sg = silu(x2b @ w1gT + b1g)   (8192 x 4096 x 1024)
  gemm2ph<256, 3><<<dim3(32, 16), 512, 0, stream>>>(bfp(OFF_X2B), bfp(OFF_W1GT), 8192, 4096, 1024,
                                                    nullptr, bfp(OFF_SG), b1g, nullptr, nullptr, nullptr, nullptr);
  // 15. sg *= (x2b @ w1xT + b1x)
  gemm2ph<256, 4><<<dim3(32, 16), 512, 0, stream>>>(bfp(OFF_X2B), bfp(OFF_W1XT), 8192, 4096, 1024,
                                                    nullptr, bfp(OFF_SG), b1x, nullptr, nullptr, nullptr, bfp(OFF_SG));
  // 16. out = ls2*(sg @ w2T + b2) + x2   (8192 x 1024 x 4096)
  gemm2ph<128, 5><<<dim3(64, 4), 512, 0, stream>>>(bfp(OFF_SG), bfp(OFF_W2T), 8192, 1024, 4096,
                                                   (float*)d_out, nullptr, b2, ls2, nullptr, ffp(OFF_X2), nullptr);
}

// Round 14
// 886.474 us; speedup vs baseline: 1.2013x; 1.1245x over previous
//
#include <hip/hip_runtime.h>
#include <hip/hip_bf16.h>
#include <math.h>

// ---------------------------------------------------------------------------
// CrossAttentionBlock on MI355X (gfx950) — round 13: T1 swizzle reverted
// (L3-fit regime -> it cost ~90µs, per m160's caveat). New: MLP steps 14+15
// fused into ONE GEMM via 16-wide column-interleaved weights (W1I) — the
// silu(g)*x pairing is lane-local in the fragment layout (EPI=6).
// GEMM schedule = proven r5 2-phase BK=64; attention = proven r7.
// B=4 N=2048 M=1024 C=1024 H=16 HD=64 HID=4096
// ---------------------------------------------------------------------------

typedef __attribute__((ext_vector_type(8))) short bf16x8;   // 8 bf16 in 4 VGPRs
typedef __attribute__((ext_vector_type(4))) short s16x4;    // 4 bf16 (8B)
typedef __attribute__((ext_vector_type(4))) float f32x4;

#define DEV __device__ __forceinline__

DEV unsigned short f2us(float f) {
  __hip_bfloat16 h = __float2bfloat16(f);
  return __builtin_bit_cast(unsigned short, h);
}

DEV void gload_lds16(const void* g, void* l) {
  __builtin_amdgcn_global_load_lds((const __attribute__((address_space(1))) void*)g,
                                   (__attribute__((address_space(3))) void*)l, 16, 0, 0);
}

#define MFMA_BF16_16x16x32 __builtin_amdgcn_mfma_f32_16x16x32_bf16
#define WAITV0 asm volatile("s_waitcnt vmcnt(0)" ::: "memory")

// ------------------------- elementwise converts ----------------------------

__global__ __launch_bounds__(256) void cvt_f32_bf16(const float* __restrict__ in,
                                                    __hip_bfloat16* __restrict__ out,
                                                    long n) {
  long i = ((long)blockIdx.x * blockDim.x + threadIdx.x) * 4;
  if (i + 3 < n) {
    float4 v = *(const float4*)(in + i);
    out[i + 0] = __float2bfloat16(v.x);
    out[i + 1] = __float2bfloat16(v.y);
    out[i + 2] = __float2bfloat16(v.z);
    out[i + 3] = __float2bfloat16(v.w);
  }
}

// w (K,N) fp32 row-major -> wT (N,K) bf16 row-major
__global__ __launch_bounds__(256) void transpose_cvt(const float* __restrict__ w,
                                                     __hip_bfloat16* __restrict__ wT,
                                                     int K, int N) {
  __shared__ float tile[32][33];
  int n0 = blockIdx.x * 32, k0 = blockIdx.y * 32;
  int tx = threadIdx.x, ty = threadIdx.y;
  #pragma unroll
  for (int i = 0; i < 32; i += 8)
    tile[ty + i][tx] = w[(long)(k0 + ty + i) * N + n0 + tx];
  __syncthreads();
  #pragma unroll
  for (int i = 0; i < 32; i += 8)
    wT[(long)(n0 + ty + i) * K + k0 + tx] = __float2bfloat16(tile[tx][ty + i]);
}

// w (1024, 4096) fp32 -> interleaved-transposed bf16: source col j goes to
// output row r = 32*(j>>4) + (j&15) + ofs  (ofs=0 for w1g, 16 for w1x).
__global__ __launch_bounds__(256) void transpose_cvt_ilv(const float* __restrict__ w,
                                                         __hip_bfloat16* __restrict__ wI,
                                                         int K, int N, int ofs) {
  __shared__ float tile[32][33];
  int n0 = blockIdx.x * 32, k0 = blockIdx.y * 32;
  int tx = threadIdx.x, ty = threadIdx.y;
  #pragma unroll
  for (int i = 0; i < 32; i += 8)
    tile[ty + i][tx] = w[(long)(k0 + ty + i) * N + n0 + tx];
  __syncthreads();
  #pragma unroll
  for (int i = 0; i < 32; i += 8) {
    int j = n0 + ty + i;
    int r = 32 * (j >> 4) + (j & 15) + ofs;
    wI[(long)r * K + k0 + tx] = __float2bfloat16(tile[tx][ty + i]);
  }
}

// V (strided, bf16) -> V^T tiled [bh][Nkv/64][64 d][72 kv(padded)] (bf16)
__global__ __launch_bounds__(256) void transpose_v(const __hip_bfloat16* __restrict__ v,
                                                   long vBatch, long vRow,
                                                   __hip_bfloat16* __restrict__ vt,
                                                   int Nkv) {
  __shared__ unsigned short tile[32][36];
  int bh = blockIdx.z;
  int b = bh >> 4, h = bh & 15;
  int kv0 = blockIdx.x * 32;
  int d0 = blockIdx.y * 32;
  int tx = threadIdx.x, ty = threadIdx.y;   // (32,8)
  const __hip_bfloat16* src = v + (long)b * vBatch + h * 64 + d0;
  #pragma unroll
  for (int i = 0; i < 32; i += 8)
    tile[ty + i][tx] = __builtin_bit_cast(unsigned short, src[(long)(kv0 + ty + i) * vRow + tx]);
  __syncthreads();
  unsigned short* dst = (unsigned short*)vt + ((long)bh * (Nkv >> 6) + (kv0 >> 6)) * 4608 + (kv0 & 32) + tx;
  #pragma unroll
  for (int i = 0; i < 32; i += 8)
    dst[(long)(d0 + ty + i) * 72] = tile[tx][ty + i];
}

// ------------------------------ LN + RoPE ----------------------------------
__global__ __launch_bounds__(256) void ln_rope(__hip_bfloat16* __restrict__ buf,
                                               const float* __restrict__ rope,
                                               const float* __restrict__ g0,
                                               const float* __restrict__ b0,
                                               const float* __restrict__ g1,
                                               const float* __restrict__ b1,
                                               int Rows, int W,
                                               long rowStride, long whichStride,
                                               int ropeMask, long total) {
  int lane = threadIdx.x & 63;
  int wv = threadIdx.x >> 6;
  long id = (long)blockIdx.x * 4 + wv;
  if (id >= total) return;
  int which = (int)(id % W);
  long t = id / W;
  int h = (int)(t & 15); t >>= 4;
  int n = (int)(t % Rows);
  int b = (int)(t / Rows);
  __hip_bfloat16* p = buf + ((long)b * Rows + n) * rowStride + (long)which * whichStride + h * 64 + lane;
  float v = __bfloat162float(*p);
  float s = v;
  #pragma unroll
  for (int m = 32; m; m >>= 1) s += __shfl_xor(s, m);
  float mean = s * (1.f / 64.f);
  float d = v - mean;
  float q = d * d;
  #pragma unroll
  for (int m = 32; m; m >>= 1) q += __shfl_xor(q, m);
  float rstd = rsqrtf(q * (1.f / 64.f) + 1e-6f);
  const float* g = which ? g1 : g0;
  const float* bb = which ? b1 : b0;
  float xn = d * rstd * g[lane] + bb[lane];
  if ((ropeMask >> which) & 1) {
    float partner = __shfl_xor(xn, 1);
    float sn = rope[(long)n * 128 + lane];
    float cs = rope[(long)n * 128 + 64 + lane];
    xn = (lane & 1) ? (xn * cs + partner * sn) : (xn * cs - partner * sn);
  }
  *p = __float2bfloat16(xn);
}

// --------------------- epilogue helper (shared by GEMMs) -------------------
template <int EPI>
DEV void epi_store(long idx, long col, float v,
                   float* __restrict__ out_f, __hip_bfloat16* __restrict__ out_b,
                   const float* __restrict__ bias, const float* __restrict__ scale,
                   const float* __restrict__ gate, const float* __restrict__ resid,
                   const __hip_bfloat16* __restrict__ mulin) {
  if constexpr (EPI == 0) {
    out_b[idx] = __float2bfloat16(v);
  } else if constexpr (EPI == 1) {
    float r = scale[col] * (v + bias[col]) + resid[idx];
    out_f[idx] = r;
    out_b[idx] = __float2bfloat16(r);
  } else if constexpr (EPI == 2) {
    float r = scale[col] * ((v + bias[col]) * tanhf(gate[col])) + resid[idx];
    out_f[idx] = r;
    out_b[idx] = __float2bfloat16(r);
  } else if constexpr (EPI == 3) {
    float z = v + bias[col];
    out_b[idx] = __float2bfloat16(z / (1.f + expf(-z)));
  } else if constexpr (EPI == 4) {
    float z = (v + bias[col]) * __bfloat162float(mulin[idx]);
    out_b[idx] = __float2bfloat16(z);
  } else {
    out_f[idx] = scale[col] * (v + bias[col]) + resid[idx];
  }
}

// ------------------------------ GEMM 128² (legacy, small shapes) -----------
template <int EPI>
__global__ __launch_bounds__(256) void gemm128(const __hip_bfloat16* __restrict__ A,
                                               const __hip_bfloat16* __restrict__ Bt,
                                               int M, int N, int K,
                                               float* __restrict__ out_f,
                                               __hip_bfloat16* __restrict__ out_b,
                                               const float* __restrict__ bias,
                                               const float* __restrict__ scale,
                                               const float* __restrict__ gate,
                                               const float* __restrict__ resid,
                                               const __hip_bfloat16* __restrict__ mulin) {
  __shared__ unsigned short As[128 * 32];
  __shared__ unsigned short Bs[128 * 32];
  int t = threadIdx.x;
  int l = t & 63;
  int w = t >> 6;
  int wr = w >> 1, wc = w & 1;
  long bm = blockIdx.x, bn = blockIdx.y;
  const __hip_bfloat16* Ab = A + bm * 128 * (long)K;
  const __hip_bfloat16* Bb = Bt + bn * 128 * (long)K;

  f32x4 acc[4][4] = {};

  for (int k0 = 0; k0 < K; k0 += 32) {
    #pragma unroll
    for (int j = 0; j < 2; j++) {
      int c = j * 256 + t;
      int row = c >> 2;
      int ko = (c & 3) * 8;
      gload_lds16(Ab + (long)row * K + k0 + ko, &As[c * 8]);
      gload_lds16(Bb + (long)row * K + k0 + ko, &Bs[c * 8]);
    }
    __syncthreads();
    bf16x8 af[4], bfg[4];
    #pragma unroll
    for (int m = 0; m < 4; m++)
      af[m] = *(const bf16x8*)&As[(wr * 64 + m * 16 + (l & 15)) * 32 + (l >> 4) * 8];
    #pragma unroll
    for (int n = 0; n < 4; n++)
      bfg[n] = *(const bf16x8*)&Bs[(wc * 64 + n * 16 + (l & 15)) * 32 + (l >> 4) * 8];
    #pragma unroll
    for (int m = 0; m < 4; m++)
      #pragma unroll
      for (int n = 0; n < 4; n++)
        acc[m][n] = MFMA_BF16_16x16x32(af[m], bfg[n], acc[m][n], 0, 0, 0);
    __syncthreads();
  }

  #pragma unroll
  for (int m = 0; m < 4; m++)
    #pragma unroll
    for (int n = 0; n < 4; n++)
      #pragma unroll
      for (int i = 0; i < 4; i++) {
        long row = bm * 128 + wr * 64 + m * 16 + (l >> 4) * 4 + i;
        long col = bn * 128 + wc * 64 + n * 16 + (l & 15);
        epi_store<EPI>(row * (long)N + col, col, acc[m][n][i],
                       out_f, out_b, bias, scale, gate, resid, mulin);
      }
}

// --------------- GEMM BMx256, BK=64, 2-phase (T3 minimum, r5) --------------
// 512 threads = 8 waves (2 M x 4 N). Double-buffered LDS; per K-tile:
// {stage(t+1) -> ds_read frags -> setprio MFMA -> vmcnt(0) -> s_barrier}.
// 3-bit chunk swizzle (c ^= row&7) on BOTH gload source and ds_read address.
// EPI=6: fused SwiGLU over 16-wide interleaved W1I columns — even-n frags
// hold g-cols, odd-n frags hold x-cols of the SAME output column (lane-local
// pairing); output ld = N/2, bias=b1g via `bias`, b1x via `gate`.
template <int BM, int EPI>
__global__ __launch_bounds__(512, 2) void gemm2ph(const __hip_bfloat16* __restrict__ A,
                                                  const __hip_bfloat16* __restrict__ Bt,
                                                  int M, int N, int K,
                                                  float* __restrict__ out_f,
                                                  __hip_bfloat16* __restrict__ out_b,
                                                  const float* __restrict__ bias,
                                                  const float* __restrict__ scale,
                                                  const float* __restrict__ gate,
                                                  const float* __restrict__ resid,
                                                  const __hip_bfloat16* __restrict__ mulin) {
  constexpr int MF = BM / 32;          // m-frags per wave (8 or 4)
  constexpr int WRS = BM / 2;          // wave row span
  constexpr int AJ = BM * 8 / 512;     // A chunks per thread (4 or 2)
  __shared__ __align__(16) unsigned short As[2][BM * 64];
  __shared__ __align__(16) unsigned short Bs[2][256 * 64];

  int t = threadIdx.x;
  int l = t & 63, w = t >> 6;
  int lo = l & 15, hi = l >> 4;
  int wr = w >> 2, wc = w & 3;         // 2 x 4 waves
  long bm = blockIdx.x, bn = blockIdx.y;
  const __hip_bfloat16* Ab = A + bm * BM * (long)K;
  const __hip_bfloat16* Bb = Bt + bn * 256 * (long)K;
  int nt = K >> 6;

  auto stage = [&](int kt, int buf) {
    long kb = (long)kt * 64;
    #pragma unroll
    for (int j = 0; j < AJ; j++) {
      int q = j * 512 + t;
      int row = q >> 3, c = (q & 7) ^ (row & 7);
      gload_lds16(Ab + (long)row * K + kb + c * 8, &As[buf][q * 8]);
    }
    #pragma unroll
    for (int j = 0; j < 4; j++) {
      int q = j * 512 + t;
      int row = q >> 3, c = (q & 7) ^ (row & 7);
      gload_lds16(Bb + (long)row * K + kb + c * 8, &Bs[buf][q * 8]);
    }
  };

  f32x4 acc[MF][4] = {};

  stage(0, 0);
  WAITV0;
  __builtin_amdgcn_s_barrier();

  for (int kt = 0; kt < nt; ++kt) {
    int cur = kt & 1;
    if (kt + 1 < nt) stage(kt + 1, cur ^ 1);

    #pragma unroll
    for (int ks = 0; ks < 2; ks++) {
      bf16x8 bfrag[4];
      #pragma unroll
      for (int n = 0; n < 4; n++) {
        int rb = wc * 64 + n * 16 + lo;
        bfrag[n] = *(const bf16x8*)&Bs[cur][rb * 64 + (((ks << 2) | hi) ^ (rb & 7)) * 8];
      }
      #pragma unroll
      for (int mg = 0; mg < MF; mg += 4) {
        bf16x8 afrag[4];
        #pragma unroll
        for (int m = 0; m < 4; m++) {
          int ra = wr * WRS + (mg + m) * 16 + lo;
          afrag[m] = *(const bf16x8*)&As[cur][ra * 64 + (((ks << 2) | hi) ^ (ra & 7)) * 8];
        }
        __builtin_amdgcn_s_setprio(1);
        #pragma unroll
        for (int m = 0; m < 4; m++)
          #pragma unroll
          for (int n = 0; n < 4; n++)
            acc[mg + m][n] = MFMA_BF16_16x16x32(afrag[m], bfrag[n], acc[mg + m][n], 0, 0, 0);
        __builtin_amdgcn_s_setprio(0);
      }
    }

    if (kt + 1 < nt) {
      WAITV0;                          // next tile fully in LDS (issued early)
      __builtin_amdgcn_s_barrier();    // all waves' reads of cur done too
    }
  }

  if constexpr (EPI == 6) {
    #pragma unroll
    for (int m = 0; m < MF; m++)
      #pragma unroll
      for (int np = 0; np < 2; np++)
        #pragma unroll
        for (int i = 0; i < 4; i++) {
          long row = bm * BM + wr * WRS + m * 16 + hi * 4 + i;
          long jc = bn * 128 + wc * 32 + np * 16 + lo;
          float g = acc[m][np * 2][i] + bias[jc];
          float xv = acc[m][np * 2 + 1][i] + gate[jc];
          float hv = (g / (1.f + expf(-g))) * xv;
          out_b[row * (long)(N >> 1) + jc] = __float2bfloat16(hv);
        }
  } else {
    #pragma unroll
    for (int m = 0; m < MF; m++)
      #pragma unroll
      for (int n = 0; n < 4; n++)
        #pragma unroll
        for (int i = 0; i < 4; i++) {
          long row = bm * BM + wr * WRS + m * 16 + hi * 4 + i;
          long col = bn * 256 + wc * 64 + n * 16 + lo;
          epi_store<EPI>(row * (long)N + col, col, acc[m][n][i],
                         out_f, out_b, bias, scale, gate, resid, mulin);
        }
  }
}

// ---------------------------- attention ------------------------------------
// r7 version (measured 184 µs SA): 4 waves/block, 32 q-rows/wave, KVBLK=64,
// swapped QK^T, defer-max, V^T LDS dbuf, K register double-buffer with NAMED
// kgA/kgB and 2-tile unrolled loop (K(t+1) issued before softmax/PV of t).
__global__ __launch_bounds__(256) void attn32(const __hip_bfloat16* __restrict__ qB, long qBatch, long qRow,
                                              const __hip_bfloat16* __restrict__ kB, long kBatch, long kRow,
                                              const __hip_bfloat16* __restrict__ vt,
                                              __hip_bfloat16* __restrict__ out, int Nq, int Nkv) {
  const float SC2 = 0.125f * 1.44269504089f;   // scale * log2(e)
  int t = threadIdx.x;
  int l = t & 63, w = t >> 6;
  int lo = l & 15, hi = l >> 4;
  int nQC = Nq >> 7;
  int qc = blockIdx.x % nQC;
  int bh = blockIdx.x / nQC;
  int h = bh & 15, b = bh >> 4;
  int q0 = qc * 128 + w * 32;

  __shared__ unsigned short P_all[4][32 * 72];
  __shared__ unsigned short V_lds[2][64 * 72];
  unsigned short* P = P_all[w];

  bf16x8 qf[2][2];
#pragma unroll
  for (int qs = 0; qs < 2; qs++) {
    const __hip_bfloat16* qp = qB + (long)b * qBatch + (long)(q0 + qs * 16 + lo) * qRow + h * 64 + hi * 8;
    qf[qs][0] = *(const bf16x8*)qp;
    qf[qs][1] = *(const bf16x8*)(qp + 32);
  }

  float mrow[2] = {-INFINITY, -INFINITY};
  float lsum[2] = {0.f, 0.f};
  f32x4 acc[2][4] = {};
  const f32x4 fz = {0.f, 0.f, 0.f, 0.f};

  const __hip_bfloat16* kbase = kB + (long)b * kBatch + h * 64 + hi * 8;
  int nt = Nkv >> 6;   // even (32 or 16)
  const char* vtb = (const char*)vt + (long)bh * nt * 9216;

  auto stageV = [&](int tile, unsigned short* dstb) {
    const char* src = vtb + (long)tile * 9216;
    gload_lds16(src + t * 16, &dstb[t * 8]);
    gload_lds16(src + (t + 256) * 16, &dstb[(t + 256) * 8]);
    if (t < 64) gload_lds16(src + (t + 512) * 16, &dstb[(t + 512) * 8]);
  };
  auto loadK = [&](int tile, bf16x8 (&kg)[4][2]) {
#pragma unroll
    for (int g = 0; g < 4; g++) {
      const __hip_bfloat16* kp = kbase + (long)(tile * 64 + g * 16 + lo) * kRow;
      kg[g][0] = *(const bf16x8*)kp;
      kg[g][1] = *(const bf16x8*)(kp + 32);
    }
  };
  auto qkt = [&](bf16x8 (&kg)[4][2], f32x4 (&ST)[2][4]) {
#pragma unroll
    for (int qs = 0; qs < 2; qs++)
#pragma unroll
      for (int g = 0; g < 4; g++) {
        f32x4 s0 = MFMA_BF16_16x16x32(kg[g][0], qf[qs][0], fz, 0, 0, 0);
        ST[qs][g] = MFMA_BF16_16x16x32(kg[g][1], qf[qs][1], s0, 0, 0, 0);
      }
  };
  auto smax = [&](f32x4 (&ST)[2][4]) {
#pragma unroll
    for (int qs = 0; qs < 2; qs++) {
      float mg0 = fmaxf(fmaxf(ST[qs][0][0], ST[qs][0][1]), fmaxf(ST[qs][0][2], ST[qs][0][3]));
      float mg1 = fmaxf(fmaxf(ST[qs][1][0], ST[qs][1][1]), fmaxf(ST[qs][1][2], ST[qs][1][3]));
      float mg2 = fmaxf(fmaxf(ST[qs][2][0], ST[qs][2][1]), fmaxf(ST[qs][2][2], ST[qs][2][3]));
      float mg3 = fmaxf(fmaxf(ST[qs][3][0], ST[qs][3][1]), fmaxf(ST[qs][3][2], ST[qs][3][3]));
      float rm = fmaxf(fmaxf(mg0, mg1), fmaxf(mg2, mg3)) * SC2;
      rm = fmaxf(rm, __shfl_xor(rm, 16));
      rm = fmaxf(rm, __shfl_xor(rm, 32));
      if (!__all(rm <= mrow[qs] + 8.f)) {     // defer-max (T13)
        float mn = fmaxf(mrow[qs], rm);
        float scl = exp2f(mrow[qs] - mn);
        mrow[qs] = mn;
        lsum[qs] *= scl;
        float c0 = __shfl(scl, hi * 4 + 0);
        float c1 = __shfl(scl, hi * 4 + 1);
        float c2 = __shfl(scl, hi * 4 + 2);
        float c3 = __shfl(scl, hi * 4 + 3);
#pragma unroll
        for (int tt = 0; tt < 4; tt++) {
          acc[qs][tt][0] *= c0; acc[qs][tt][1] *= c1;
          acc[qs][tt][2] *= c2; acc[qs][tt][3] *= c3;
        }
      }
      float m = mrow[qs];
      float rs = 0.f;
#pragma unroll
      for (int g = 0; g < 4; g++) {
        float p0 = exp2f(fmaf(ST[qs][g][0], SC2, -m));
        float p1 = exp2f(fmaf(ST[qs][g][1], SC2, -m));
        float p2 = exp2f(fmaf(ST[qs][g][2], SC2, -m));
        float p3 = exp2f(fmaf(ST[qs][g][3], SC2, -m));
        rs += (p0 + p1) + (p2 + p3);
        s16x4 pw;
        pw[0] = (short)f2us(p0); pw[1] = (short)f2us(p1);
        pw[2] = (short)f2us(p2); pw[3] = (short)f2us(p3);
        *(s16x4*)&P[(qs * 16 + lo) * 72 + g * 16 + hi * 4] = pw;
      }
      rs += __shfl_xor(rs, 16);
      rs += __shfl_xor(rs, 32);
      lsum[qs] += rs;
    }
  };
  auto pv = [&](const unsigned short* Vb) {
    bf16x8 pf[2][2];
#pragma unroll
    for (int qs = 0; qs < 2; qs++) {
      pf[qs][0] = *(const bf16x8*)&P[(qs * 16 + lo) * 72 + hi * 8];
      pf[qs][1] = *(const bf16x8*)&P[(qs * 16 + lo) * 72 + 32 + hi * 8];
    }
#pragma unroll
    for (int tt = 0; tt < 4; tt++) {
      bf16x8 v0 = *(const bf16x8*)&Vb[(tt * 16 + lo) * 72 + hi * 8];
      bf16x8 v1 = *(const bf16x8*)&Vb[(tt * 16 + lo) * 72 + 32 + hi * 8];
#pragma unroll
      for (int qs = 0; qs < 2; qs++) {
        acc[qs][tt] = MFMA_BF16_16x16x32(pf[qs][0], v0, acc[qs][tt], 0, 0, 0);
        acc[qs][tt] = MFMA_BF16_16x16x32(pf[qs][1], v1, acc[qs][tt], 0, 0, 0);
      }
    }
  };

  // prologue: V tile 0 -> buf0; K tile 0 -> kgA
  bf16x8 kgA[4][2], kgB[4][2];
  stageV(0, V_lds[0]);
  loadK(0, kgA);

  for (int it = 0; it < nt; it += 2) {
    __syncthreads();                       // V[it]@buf0 + K[it] complete (vmcnt drain)
    stageV(it + 1, V_lds[1]);              // nt even -> it+1 < nt always
    f32x4 ST0[2][4];
    qkt(kgA, ST0);
    loadK(it + 1, kgB);                    // hide K latency under softmax+PV
    smax(ST0);
    pv(V_lds[0]);

    __syncthreads();                       // V[it+1]@buf1 + K[it+1] complete
    if (it + 2 < nt) stageV(it + 2, V_lds[0]);
    f32x4 ST1[2][4];
    qkt(kgB, ST1);
    if (it + 2 < nt) loadK(it + 2, kgA);
    smax(ST1);
    pv(V_lds[1]);
  }

#pragma unroll
  for (int qs = 0; qs < 2; qs++) {
    float inv = 1.f / lsum[qs];
    float iv0 = __shfl(inv, hi * 4 + 0);
    float iv1 = __shfl(inv, hi * 4 + 1);
    float iv2 = __shfl(inv, hi * 4 + 2);
    float iv3 = __shfl(inv, hi * 4 + 3);
    float iv[4] = {iv0, iv1, iv2, iv3};
#pragma unroll
    for (int i = 0; i < 4; i++) {
      long row = q0 + qs * 16 + hi * 4 + i;
      __hip_bfloat16* op = out + ((long)b * Nq + row) * 1024 + h * 64 + lo;
#pragma unroll
      for (int tt = 0; tt < 4; tt++) op[tt * 16] = __float2bfloat16(acc[qs][tt][i] * iv[i]);
    }
  }
}

// ------------------------------ launch -------------------------------------

extern "C" void kernel_launch(void* const* d_in, const int* in_sizes, int n_in,
                              void* d_out, int out_size, void* d_ws, size_t ws_size,
                              hipStream_t stream) {
  (void)in_sizes; (void)n_in; (void)out_size; (void)ws_size;

  const float* x      = (const float*)d_in[0];
  const float* ctx    = (const float*)d_in[1];
  const float* rope   = (const float*)d_in[2];
  const float* wqkv   = (const float*)d_in[3];
  const float* sa_qg  = (const float*)d_in[4];
  const float* sa_qb  = (const float*)d_in[5];
  const float* sa_kg  = (const float*)d_in[6];
  const float* sa_kb  = (const float*)d_in[7];
  const float* sa_wo  = (const float*)d_in[8];
  const float* sa_bo  = (const float*)d_in[9];
  const float* ca_wq  = (const float*)d_in[10];
  const float* ca_wk  = (const float*)d_in[11];
  const float* ca_wv  = (const float*)d_in[12];
  const float* ca_qg  = (const float*)d_in[13];
  const float* ca_qb  = (const float*)d_in[14];
  const float* ca_kg  = (const float*)d_in[15];
  const float* ca_kb  = (const float*)d_in[16];
  const float* ca_wo  = (const float*)d_in[17];
  const float* ca_bo  = (const float*)d_in[18];
  const float* ca_gate= (const float*)d_in[19];
  const float* w1g    = (const float*)d_in[20];
  const float* b1g    = (const float*)d_in[21];
  const float* w1x    = (const float*)d_in[22];
  const float* b1x    = (const float*)d_in[23];
  const float* w2     = (const float*)d_in[24];
  const float* b2     = (const float*)d_in[25];
  const float* ls0    = (const float*)d_in[26];
  const float* ls1    = (const float*)d_in[27];
  const float* ls2    = (const float*)d_in[28];

  char* ws = (char*)d_ws;

  // workspace layout (bytes); peak 218,103,808 (208 MiB), manual reuse
  const long OFF_WQKVT = 0;
  const long OFF_SAWOT = 6291456;
  const long OFF_CAWQT = 8388608;
  const long OFF_CAWKT = 10485760;
  const long OFF_CAWVT = 12582912;
  const long OFF_CAWOT = 14680064;
  const long OFF_W1I   = 16777216;   // 16 MB interleaved w1g/w1x (8192x1024)
  const long OFF_W2T   = 33554432;
  const long OFF_XB    = 41943040;   // 16 MB (dead after qkv gemm)
  const long OFF_QC    = OFF_XB;     //   reuse
  const long OFF_CTXB  = 58720256;
  const long OFF_QKV   = 67108864;   // 48 MB (dead after SA attn)
  const long OFF_CAO   = 67108864;
  const long OFF_X2B   = 83886080;
  const long OFF_SG    = 100663296;  // 64 MB region (SG uses 67 MB... 8192x4096x2B = 64 MB)
  const long OFF_SAO   = 117440512;
  const long OFF_KC    = 117440512;
  const long OFF_VC    = 125829120;
  const long OFF_X1    = 134217728;
  const long OFF_X1B   = 167772160;  // 16 MB (dead after ca_wq gemm)
  const long OFF_CAVT  = OFF_X1B;    //   reuse: CA V^T tiled (9,437,184)
  const long OFF_X2    = 184549376;  // 33.5 MB (written at step 13)
  const long OFF_SAVT  = OFF_X2;     //   reuse: SA V^T tiled (18,874,368), dead after SA attn

  auto bfp = [&](long off) { return (__hip_bfloat16*)(ws + off); };
  auto ffp = [&](long off) { return (float*)(ws + off); };

  dim3 tb32(32, 8);
  // 1. weight transposes
  transpose_cvt<<<dim3(96, 32), tb32, 0, stream>>>(wqkv,  bfp(OFF_WQKVT), 1024, 3072);
  transpose_cvt<<<dim3(32, 32), tb32, 0, stream>>>(sa_wo, bfp(OFF_SAWOT), 1024, 1024);
  transpose_cvt<<<dim3(32, 32), tb32, 0, stream>>>(ca_wq, bfp(OFF_CAWQT), 1024, 1024);
  transpose_cvt<<<dim3(32, 32), tb32, 0, stream>>>(ca_wk, bfp(OFF_CAWKT), 1024, 1024);
  transpose_cvt<<<dim3(32, 32), tb32, 0, stream>>>(ca_wv, bfp(OFF_CAWVT), 1024, 1024);
  transpose_cvt<<<dim3(32, 32), tb32, 0, stream>>>(ca_wo, bfp(OFF_CAWOT), 1024, 1024);
  transpose_cvt_ilv<<<dim3(128, 32), tb32, 0, stream>>>(w1g, bfp(OFF_W1I), 1024, 4096, 0);
  transpose_cvt_ilv<<<dim3(128, 32), tb32, 0, stream>>>(w1x, bfp(OFF_W1I), 1024, 4096, 16);
  transpose_cvt<<<dim3(32, 128), tb32, 0, stream>>>(w2,   bfp(OFF_W2T), 4096, 1024);

  // 2. activations -> bf16
  cvt_f32_bf16<<<8192, 256, 0, stream>>>(x,   bfp(OFF_XB),   8388608);
  cvt_f32_bf16<<<4096, 256, 0, stream>>>(ctx, bfp(OFF_CTXB), 4194304);

  // 3. qkv = xb @ wqkvT   (8192 x 3072 x 1024)
  gemm2ph<256, 0><<<dim3(32, 12), 512, 0, stream>>>(bfp(OFF_XB), bfp(OFF_WQKVT), 8192, 3072, 1024,
                                                    nullptr, bfp(OFF_QKV), nullptr, nullptr, nullptr, nullptr, nullptr);

  // 3b. SA V^T (tiled+padded; X2 region free until step 13)
  transpose_v<<<dim3(64, 2, 64), tb32, 0, stream>>>(bfp(OFF_QKV) + 2048, (long)2048 * 3072, 3072,
                                                    bfp(OFF_SAVT), 2048);

  // 4. SA LN + rope on q,k (in place in qkv)
  ln_rope<<<65536, 256, 0, stream>>>(bfp(OFF_QKV), rope, sa_qg, sa_qb, sa_kg, sa_kb,
                                     2048, 2, 3 * 1024, 1024, 3, (long)4 * 2048 * 16 * 2);

  // 5. self-attention
  attn32<<<1024, 256, 0, stream>>>(bfp(OFF_QKV),        (long)2048 * 3072, 3072,
                                   bfp(OFF_QKV) + 1024, (long)2048 * 3072, 3072,
                                   bfp(OFF_SAVT), bfp(OFF_SAO), 2048, 2048);

  // 6. sa proj + residual: x1 = ls0*(sa@wo + bo) + x   (8192 x 1024 x 1024)
  gemm2ph<128, 1><<<dim3(64, 4), 512, 0, stream>>>(bfp(OFF_SAO), bfp(OFF_SAWOT), 8192, 1024, 1024,
                                                   ffp(OFF_X1), bfp(OFF_X1B), sa_bo, ls0, nullptr, x, nullptr);

  // 7-9. CA projections
  gemm2ph<128, 0><<<dim3(64, 4), 512, 0, stream>>>(bfp(OFF_X1B), bfp(OFF_CAWQT), 8192, 1024, 1024,
                                                   nullptr, bfp(OFF_QC), nullptr, nullptr, nullptr, nullptr, nullptr);
  gemm128<0><<<dim3(32, 8), 256, 0, stream>>>(bfp(OFF_CTXB), bfp(OFF_CAWKT), 4096, 1024, 1024,
                                              nullptr, bfp(OFF_KC), nullptr, nullptr, nullptr, nullptr, nullptr);
  gemm128<0><<<dim3(32, 8), 256, 0, stream>>>(bfp(OFF_CTXB), bfp(OFF_CAWVT), 4096, 1024, 1024,
                                              nullptr, bfp(OFF_VC), nullptr, nullptr, nullptr, nullptr, nullptr);

  // 9b. CA V^T (tiled+padded; X1B dead after ca_wq gemm)
  transpose_v<<<dim3(32, 2, 64), tb32, 0, stream>>>(bfp(OFF_VC), (long)1024 * 1024, 1024,
                                                    bfp(OFF_CAVT), 1024);

  // 10-11. CA LN (+rope on q only)
  ln_rope<<<32768, 256, 0, stream>>>(bfp(OFF_QC), rope, ca_qg, ca_qb, ca_qg, ca_qb,
                                     2048, 1, 1024, 0, 1, (long)4 * 2048 * 16);
  ln_rope<<<16384, 256, 0, stream>>>(bfp(OFF_KC), rope, ca_kg, ca_kb, ca_kg, ca_kb,
                                     1024, 1, 1024, 0, 0, (long)4 * 1024 * 16);

  // 12. cross-attention
  attn32<<<1024, 256, 0, stream>>>(bfp(OFF_QC), (long)2048 * 1024, 1024,
                                   bfp(OFF_KC), (long)1024 * 1024, 1024,
                                   bfp(OFF_CAVT), bfp(OFF_CAO), 2048, 1024);

  // 13. ca proj: x2 = ls1*((ca@wo + bo)*tanh(gate)) + x1
  gemm2ph<128, 2><<<dim3(64, 4), 512, 0, stream>>>(bfp(OFF_CAO), bfp(OFF_CAWOT), 8192, 1024, 1024,
                                                   ffp(OFF_X2), bfp(OFF_X2B), ca_bo, ls1, ca_gate, ffp(OFF_X1), nullptr);

  // 14. FUSED MLP up: sg = silu(x2b@w1g + b1g) * (x2b@w1x + b1x)
  //     one GEMM over interleaved W1I (8192 x 8192 x 1024), EPI=6
  gemm2ph<256, 6><<<dim3(32, 32), 512, 0, stream>>>(bfp(OFF_X2B), bfp(OFF_W1I), 8192, 8192, 1024,
                                                    nullptr, bfp(OFF_SG), b1g, nullptr, b1x, nullptr, nullptr);

  // 16. out = ls2*(sg @ w2T + b2) + x2   (8192 x 1024 x 4096)
  gemm2ph<128, 5><<<dim3(64, 4), 512, 0, stream>>>(bfp(OFF_SG), bfp(OFF_W2T), 8192, 1024, 4096,
                                                   (float*)d_out, nullptr, b2, ls2, nullptr, ffp(OFF_X2), nullptr);
}

// Round 15
// 878.329 us; speedup vs baseline: 1.2124x; 1.0093x over previous
//
#include <hip/hip_runtime.h>
#include <hip/hip_bf16.h>
#include <math.h>

// ---------------------------------------------------------------------------
// CrossAttentionBlock on MI355X (gfx950) — round 14: three low-risk levers on
// the r13 base (886µs): (1) T5 setprio around attn MFMA clusters (m191:
// attn-positive), (2) qkv GEMM at BM=128 -> 768 blocks = 3/CU balanced (was
// 384 = 1.5 rounds, 75% util), (3) ca_wk+ca_wv merged into ONE gemm2ph over
// the contiguous stacked weights (256 blocks = full chip; gemm128 removed).
// Buffer plan: SAO @117440512 (dead after step 6), KVC (combined CA K|V,
// 16 MB) reuses the same region afterward.
// B=4 N=2048 M=1024 C=1024 H=16 HD=64 HID=4096
// ---------------------------------------------------------------------------

typedef __attribute__((ext_vector_type(8))) short bf16x8;   // 8 bf16 in 4 VGPRs
typedef __attribute__((ext_vector_type(4))) short s16x4;    // 4 bf16 (8B)
typedef __attribute__((ext_vector_type(4))) float f32x4;

#define DEV __device__ __forceinline__

DEV unsigned short f2us(float f) {
  __hip_bfloat16 h = __float2bfloat16(f);
  return __builtin_bit_cast(unsigned short, h);
}

DEV void gload_lds16(const void* g, void* l) {
  __builtin_amdgcn_global_load_lds((const __attribute__((address_space(1))) void*)g,
                                   (__attribute__((address_space(3))) void*)l, 16, 0, 0);
}

#define MFMA_BF16_16x16x32 __builtin_amdgcn_mfma_f32_16x16x32_bf16
#define WAITV0 asm volatile("s_waitcnt vmcnt(0)" ::: "memory")

// ------------------------- elementwise converts ----------------------------

__global__ __launch_bounds__(256) void cvt_f32_bf16(const float* __restrict__ in,
                                                    __hip_bfloat16* __restrict__ out,
                                                    long n) {
  long i = ((long)blockIdx.x * blockDim.x + threadIdx.x) * 4;
  if (i + 3 < n) {
    float4 v = *(const float4*)(in + i);
    out[i + 0] = __float2bfloat16(v.x);
    out[i + 1] = __float2bfloat16(v.y);
    out[i + 2] = __float2bfloat16(v.z);
    out[i + 3] = __float2bfloat16(v.w);
  }
}

// w (K,N) fp32 row-major -> wT (N,K) bf16 row-major
__global__ __launch_bounds__(256) void transpose_cvt(const float* __restrict__ w,
                                                     __hip_bfloat16* __restrict__ wT,
                                                     int K, int N) {
  __shared__ float tile[32][33];
  int n0 = blockIdx.x * 32, k0 = blockIdx.y * 32;
  int tx = threadIdx.x, ty = threadIdx.y;
  #pragma unroll
  for (int i = 0; i < 32; i += 8)
    tile[ty + i][tx] = w[(long)(k0 + ty + i) * N + n0 + tx];
  __syncthreads();
  #pragma unroll
  for (int i = 0; i < 32; i += 8)
    wT[(long)(n0 + ty + i) * K + k0 + tx] = __float2bfloat16(tile[tx][ty + i]);
}

// w (1024, 4096) fp32 -> interleaved-transposed bf16: source col j goes to
// output row r = 32*(j>>4) + (j&15) + ofs  (ofs=0 for w1g, 16 for w1x).
__global__ __launch_bounds__(256) void transpose_cvt_ilv(const float* __restrict__ w,
                                                         __hip_bfloat16* __restrict__ wI,
                                                         int K, int N, int ofs) {
  __shared__ float tile[32][33];
  int n0 = blockIdx.x * 32, k0 = blockIdx.y * 32;
  int tx = threadIdx.x, ty = threadIdx.y;
  #pragma unroll
  for (int i = 0; i < 32; i += 8)
    tile[ty + i][tx] = w[(long)(k0 + ty + i) * N + n0 + tx];
  __syncthreads();
  #pragma unroll
  for (int i = 0; i < 32; i += 8) {
    int j = n0 + ty + i;
    int r = 32 * (j >> 4) + (j & 15) + ofs;
    wI[(long)r * K + k0 + tx] = __float2bfloat16(tile[tx][ty + i]);
  }
}

// V (strided, bf16) -> V^T tiled [bh][Nkv/64][64 d][72 kv(padded)] (bf16)
__global__ __launch_bounds__(256) void transpose_v(const __hip_bfloat16* __restrict__ v,
                                                   long vBatch, long vRow,
                                                   __hip_bfloat16* __restrict__ vt,
                                                   int Nkv) {
  __shared__ unsigned short tile[32][36];
  int bh = blockIdx.z;
  int b = bh >> 4, h = bh & 15;
  int kv0 = blockIdx.x * 32;
  int d0 = blockIdx.y * 32;
  int tx = threadIdx.x, ty = threadIdx.y;   // (32,8)
  const __hip_bfloat16* src = v + (long)b * vBatch + h * 64 + d0;
  #pragma unroll
  for (int i = 0; i < 32; i += 8)
    tile[ty + i][tx] = __builtin_bit_cast(unsigned short, src[(long)(kv0 + ty + i) * vRow + tx]);
  __syncthreads();
  unsigned short* dst = (unsigned short*)vt + ((long)bh * (Nkv >> 6) + (kv0 >> 6)) * 4608 + (kv0 & 32) + tx;
  #pragma unroll
  for (int i = 0; i < 32; i += 8)
    dst[(long)(d0 + ty + i) * 72] = tile[tx][ty + i];
}

// ------------------------------ LN + RoPE ----------------------------------
__global__ __launch_bounds__(256) void ln_rope(__hip_bfloat16* __restrict__ buf,
                                               const float* __restrict__ rope,
                                               const float* __restrict__ g0,
                                               const float* __restrict__ b0,
                                               const float* __restrict__ g1,
                                               const float* __restrict__ b1,
                                               int Rows, int W,
                                               long rowStride, long whichStride,
                                               int ropeMask, long total) {
  int lane = threadIdx.x & 63;
  int wv = threadIdx.x >> 6;
  long id = (long)blockIdx.x * 4 + wv;
  if (id >= total) return;
  int which = (int)(id % W);
  long t = id / W;
  int h = (int)(t & 15); t >>= 4;
  int n = (int)(t % Rows);
  int b = (int)(t / Rows);
  __hip_bfloat16* p = buf + ((long)b * Rows + n) * rowStride + (long)which * whichStride + h * 64 + lane;
  float v = __bfloat162float(*p);
  float s = v;
  #pragma unroll
  for (int m = 32; m; m >>= 1) s += __shfl_xor(s, m);
  float mean = s * (1.f / 64.f);
  float d = v - mean;
  float q = d * d;
  #pragma unroll
  for (int m = 32; m; m >>= 1) q += __shfl_xor(q, m);
  float rstd = rsqrtf(q * (1.f / 64.f) + 1e-6f);
  const float* g = which ? g1 : g0;
  const float* bb = which ? b1 : b0;
  float xn = d * rstd * g[lane] + bb[lane];
  if ((ropeMask >> which) & 1) {
    float partner = __shfl_xor(xn, 1);
    float sn = rope[(long)n * 128 + lane];
    float cs = rope[(long)n * 128 + 64 + lane];
    xn = (lane & 1) ? (xn * cs + partner * sn) : (xn * cs - partner * sn);
  }
  *p = __float2bfloat16(xn);
}

// --------------------- epilogue helper (shared by GEMMs) -------------------
template <int EPI>
DEV void epi_store(long idx, long col, float v,
                   float* __restrict__ out_f, __hip_bfloat16* __restrict__ out_b,
                   const float* __restrict__ bias, const float* __restrict__ scale,
                   const float* __restrict__ gate, const float* __restrict__ resid,
                   const __hip_bfloat16* __restrict__ mulin) {
  if constexpr (EPI == 0) {
    out_b[idx] = __float2bfloat16(v);
  } else if constexpr (EPI == 1) {
    float r = scale[col] * (v + bias[col]) + resid[idx];
    out_f[idx] = r;
    out_b[idx] = __float2bfloat16(r);
  } else if constexpr (EPI == 2) {
    float r = scale[col] * ((v + bias[col]) * tanhf(gate[col])) + resid[idx];
    out_f[idx] = r;
    out_b[idx] = __float2bfloat16(r);
  } else if constexpr (EPI == 3) {
    float z = v + bias[col];
    out_b[idx] = __float2bfloat16(z / (1.f + expf(-z)));
  } else if constexpr (EPI == 4) {
    float z = (v + bias[col]) * __bfloat162float(mulin[idx]);
    out_b[idx] = __float2bfloat16(z);
  } else {
    out_f[idx] = scale[col] * (v + bias[col]) + resid[idx];
  }
}

// --------------- GEMM BMx256, BK=64, 2-phase (T3 minimum, r5) --------------
// EPI=6: fused SwiGLU over 16-wide interleaved W1I columns (lane-local
// pairing); output ld = N/2, b1g via `bias`, b1x via `gate`.
template <int BM, int EPI>
__global__ __launch_bounds__(512, 2) void gemm2ph(const __hip_bfloat16* __restrict__ A,
                                                  const __hip_bfloat16* __restrict__ Bt,
                                                  int M, int N, int K,
                                                  float* __restrict__ out_f,
                                                  __hip_bfloat16* __restrict__ out_b,
                                                  const float* __restrict__ bias,
                                                  const float* __restrict__ scale,
                                                  const float* __restrict__ gate,
                                                  const float* __restrict__ resid,
                                                  const __hip_bfloat16* __restrict__ mulin) {
  constexpr int MF = BM / 32;
  constexpr int WRS = BM / 2;
  constexpr int AJ = BM * 8 / 512;
  __shared__ __align__(16) unsigned short As[2][BM * 64];
  __shared__ __align__(16) unsigned short Bs[2][256 * 64];

  int t = threadIdx.x;
  int l = t & 63, w = t >> 6;
  int lo = l & 15, hi = l >> 4;
  int wr = w >> 2, wc = w & 3;
  long bm = blockIdx.x, bn = blockIdx.y;
  const __hip_bfloat16* Ab = A + bm * BM * (long)K;
  const __hip_bfloat16* Bb = Bt + bn * 256 * (long)K;
  int nt = K >> 6;

  auto stage = [&](int kt, int buf) {
    long kb = (long)kt * 64;
    #pragma unroll
    for (int j = 0; j < AJ; j++) {
      int q = j * 512 + t;
      int row = q >> 3, c = (q & 7) ^ (row & 7);
      gload_lds16(Ab + (long)row * K + kb + c * 8, &As[buf][q * 8]);
    }
    #pragma unroll
    for (int j = 0; j < 4; j++) {
      int q = j * 512 + t;
      int row = q >> 3, c = (q & 7) ^ (row & 7);
      gload_lds16(Bb + (long)row * K + kb + c * 8, &Bs[buf][q * 8]);
    }
  };

  f32x4 acc[MF][4] = {};

  stage(0, 0);
  WAITV0;
  __builtin_amdgcn_s_barrier();

  for (int kt = 0; kt < nt; ++kt) {
    int cur = kt & 1;
    if (kt + 1 < nt) stage(kt + 1, cur ^ 1);

    #pragma unroll
    for (int ks = 0; ks < 2; ks++) {
      bf16x8 bfrag[4];
      #pragma unroll
      for (int n = 0; n < 4; n++) {
        int rb = wc * 64 + n * 16 + lo;
        bfrag[n] = *(const bf16x8*)&Bs[cur][rb * 64 + (((ks << 2) | hi) ^ (rb & 7)) * 8];
      }
      #pragma unroll
      for (int mg = 0; mg < MF; mg += 4) {
        bf16x8 afrag[4];
        #pragma unroll
        for (int m = 0; m < 4; m++) {
          int ra = wr * WRS + (mg + m) * 16 + lo;
          afrag[m] = *(const bf16x8*)&As[cur][ra * 64 + (((ks << 2) | hi) ^ (ra & 7)) * 8];
        }
        __builtin_amdgcn_s_setprio(1);
        #pragma unroll
        for (int m = 0; m < 4; m++)
          #pragma unroll
          for (int n = 0; n < 4; n++)
            acc[mg + m][n] = MFMA_BF16_16x16x32(afrag[m], bfrag[n], acc[mg + m][n], 0, 0, 0);
        __builtin_amdgcn_s_setprio(0);
      }
    }

    if (kt + 1 < nt) {
      WAITV0;
      __builtin_amdgcn_s_barrier();
    }
  }

  if constexpr (EPI == 6) {
    #pragma unroll
    for (int m = 0; m < MF; m++)
      #pragma unroll
      for (int np = 0; np < 2; np++)
        #pragma unroll
        for (int i = 0; i < 4; i++) {
          long row = bm * BM + wr * WRS + m * 16 + hi * 4 + i;
          long jc = bn * 128 + wc * 32 + np * 16 + lo;
          float g = acc[m][np * 2][i] + bias[jc];
          float xv = acc[m][np * 2 + 1][i] + gate[jc];
          float hv = (g / (1.f + expf(-g))) * xv;
          out_b[row * (long)(N >> 1) + jc] = __float2bfloat16(hv);
        }
  } else {
    #pragma unroll
    for (int m = 0; m < MF; m++)
      #pragma unroll
      for (int n = 0; n < 4; n++)
        #pragma unroll
        for (int i = 0; i < 4; i++) {
          long row = bm * BM + wr * WRS + m * 16 + hi * 4 + i;
          long col = bn * 256 + wc * 64 + n * 16 + lo;
          epi_store<EPI>(row * (long)N + col, col, acc[m][n][i],
                         out_f, out_b, bias, scale, gate, resid, mulin);
        }
  }
}

// ---------------------------- attention ------------------------------------
// r7 structure + T5 setprio around MFMA clusters (m191: attn-positive).
__global__ __launch_bounds__(256) void attn32(const __hip_bfloat16* __restrict__ qB, long qBatch, long qRow,
                                              const __hip_bfloat16* __restrict__ kB, long kBatch, long kRow,
                                              const __hip_bfloat16* __restrict__ vt,
                                              __hip_bfloat16* __restrict__ out, int Nq, int Nkv) {
  const float SC2 = 0.125f * 1.44269504089f;
  int t = threadIdx.x;
  int l = t & 63, w = t >> 6;
  int lo = l & 15, hi = l >> 4;
  int nQC = Nq >> 7;
  int qc = blockIdx.x % nQC;
  int bh = blockIdx.x / nQC;
  int h = bh & 15, b = bh >> 4;
  int q0 = qc * 128 + w * 32;

  __shared__ unsigned short P_all[4][32 * 72];
  __shared__ unsigned short V_lds[2][64 * 72];
  unsigned short* P = P_all[w];

  bf16x8 qf[2][2];
#pragma unroll
  for (int qs = 0; qs < 2; qs++) {
    const __hip_bfloat16* qp = qB + (long)b * qBatch + (long)(q0 + qs * 16 + lo) * qRow + h * 64 + hi * 8;
    qf[qs][0] = *(const bf16x8*)qp;
    qf[qs][1] = *(const bf16x8*)(qp + 32);
  }

  float mrow[2] = {-INFINITY, -INFINITY};
  float lsum[2] = {0.f, 0.f};
  f32x4 acc[2][4] = {};
  const f32x4 fz = {0.f, 0.f, 0.f, 0.f};

  const __hip_bfloat16* kbase = kB + (long)b * kBatch + h * 64 + hi * 8;
  int nt = Nkv >> 6;
  const char* vtb = (const char*)vt + (long)bh * nt * 9216;

  auto stageV = [&](int tile, unsigned short* dstb) {
    const char* src = vtb + (long)tile * 9216;
    gload_lds16(src + t * 16, &dstb[t * 8]);
    gload_lds16(src + (t + 256) * 16, &dstb[(t + 256) * 8]);
    if (t < 64) gload_lds16(src + (t + 512) * 16, &dstb[(t + 512) * 8]);
  };
  auto loadK = [&](int tile, bf16x8 (&kg)[4][2]) {
#pragma unroll
    for (int g = 0; g < 4; g++) {
      const __hip_bfloat16* kp = kbase + (long)(tile * 64 + g * 16 + lo) * kRow;
      kg[g][0] = *(const bf16x8*)kp;
      kg[g][1] = *(const bf16x8*)(kp + 32);
    }
  };
  auto qkt = [&](bf16x8 (&kg)[4][2], f32x4 (&ST)[2][4]) {
    __builtin_amdgcn_s_setprio(1);
#pragma unroll
    for (int qs = 0; qs < 2; qs++)
#pragma unroll
      for (int g = 0; g < 4; g++) {
        f32x4 s0 = MFMA_BF16_16x16x32(kg[g][0], qf[qs][0], fz, 0, 0, 0);
        ST[qs][g] = MFMA_BF16_16x16x32(kg[g][1], qf[qs][1], s0, 0, 0, 0);
      }
    __builtin_amdgcn_s_setprio(0);
  };
  auto smax = [&](f32x4 (&ST)[2][4]) {
#pragma unroll
    for (int qs = 0; qs < 2; qs++) {
      float mg0 = fmaxf(fmaxf(ST[qs][0][0], ST[qs][0][1]), fmaxf(ST[qs][0][2], ST[qs][0][3]));
      float mg1 = fmaxf(fmaxf(ST[qs][1][0], ST[qs][1][1]), fmaxf(ST[qs][1][2], ST[qs][1][3]));
      float mg2 = fmaxf(fmaxf(ST[qs][2][0], ST[qs][2][1]), fmaxf(ST[qs][2][2], ST[qs][2][3]));
      float mg3 = fmaxf(fmaxf(ST[qs][3][0], ST[qs][3][1]), fmaxf(ST[qs][3][2], ST[qs][3][3]));
      float rm = fmaxf(fmaxf(mg0, mg1), fmaxf(mg2, mg3)) * SC2;
      rm = fmaxf(rm, __shfl_xor(rm, 16));
      rm = fmaxf(rm, __shfl_xor(rm, 32));
      if (!__all(rm <= mrow[qs] + 8.f)) {
        float mn = fmaxf(mrow[qs], rm);
        float scl = exp2f(mrow[qs] - mn);
        mrow[qs] = mn;
        lsum[qs] *= scl;
        float c0 = __shfl(scl, hi * 4 + 0);
        float c1 = __shfl(scl, hi * 4 + 1);
        float c2 = __shfl(scl, hi * 4 + 2);
        float c3 = __shfl(scl, hi * 4 + 3);
#pragma unroll
        for (int tt = 0; tt < 4; tt++) {
          acc[qs][tt][0] *= c0; acc[qs][tt][1] *= c1;
          acc[qs][tt][2] *= c2; acc[qs][tt][3] *= c3;
        }
      }
      float m = mrow[qs];
      float rs = 0.f;
#pragma unroll
      for (int g = 0; g < 4; g++) {
        float p0 = exp2f(fmaf(ST[qs][g][0], SC2, -m));
        float p1 = exp2f(fmaf(ST[qs][g][1], SC2, -m));
        float p2 = exp2f(fmaf(ST[qs][g][2], SC2, -m));
        float p3 = exp2f(fmaf(ST[qs][g][3], SC2, -m));
        rs += (p0 + p1) + (p2 + p3);
        s16x4 pw;
        pw[0] = (short)f2us(p0); pw[1] = (short)f2us(p1);
        pw[2] = (short)f2us(p2); pw[3] = (short)f2us(p3);
        *(s16x4*)&P[(qs * 16 + lo) * 72 + g * 16 + hi * 4] = pw;
      }
      rs += __shfl_xor(rs, 16);
      rs += __shfl_xor(rs, 32);
      lsum[qs] += rs;
    }
  };
  auto pv = [&](const unsigned short* Vb) {
    bf16x8 pf[2][2];
#pragma unroll
    for (int qs = 0; qs < 2; qs++) {
      pf[qs][0] = *(const bf16x8*)&P[(qs * 16 + lo) * 72 + hi * 8];
      pf[qs][1] = *(const bf16x8*)&P[(qs * 16 + lo) * 72 + 32 + hi * 8];
    }
    __builtin_amdgcn_s_setprio(1);
#pragma unroll
    for (int tt = 0; tt < 4; tt++) {
      bf16x8 v0 = *(const bf16x8*)&Vb[(tt * 16 + lo) * 72 + hi * 8];
      bf16x8 v1 = *(const bf16x8*)&Vb[(tt * 16 + lo) * 72 + 32 + hi * 8];
#pragma unroll
      for (int qs = 0; qs < 2; qs++) {
        acc[qs][tt] = MFMA_BF16_16x16x32(pf[qs][0], v0, acc[qs][tt], 0, 0, 0);
        acc[qs][tt] = MFMA_BF16_16x16x32(pf[qs][1], v1, acc[qs][tt], 0, 0, 0);
      }
    }
    __builtin_amdgcn_s_setprio(0);
  };

  bf16x8 kgA[4][2], kgB[4][2];
  stageV(0, V_lds[0]);
  loadK(0, kgA);

  for (int it = 0; it < nt; it += 2) {
    __syncthreads();
    stageV(it + 1, V_lds[1]);
    f32x4 ST0[2][4];
    qkt(kgA, ST0);
    loadK(it + 1, kgB);
    smax(ST0);
    pv(V_lds[0]);

    __syncthreads();
    if (it + 2 < nt) stageV(it + 2, V_lds[0]);
    f32x4 ST1[2][4];
    qkt(kgB, ST1);
    if (it + 2 < nt) loadK(it + 2, kgA);
    smax(ST1);
    pv(V_lds[1]);
  }

#pragma unroll
  for (int qs = 0; qs < 2; qs++) {
    float inv = 1.f / lsum[qs];
    float iv0 = __shfl(inv, hi * 4 + 0);
    float iv1 = __shfl(inv, hi * 4 + 1);
    float iv2 = __shfl(inv, hi * 4 + 2);
    float iv3 = __shfl(inv, hi * 4 + 3);
    float iv[4] = {iv0, iv1, iv2, iv3};
#pragma unroll
    for (int i = 0; i < 4; i++) {
      long row = q0 + qs * 16 + hi * 4 + i;
      __hip_bfloat16* op = out + ((long)b * Nq + row) * 1024 + h * 64 + lo;
#pragma unroll
      for (int tt = 0; tt < 4; tt++) op[tt * 16] = __float2bfloat16(acc[qs][tt][i] * iv[i]);
    }
  }
}

// ------------------------------ launch -------------------------------------

extern "C" void kernel_launch(void* const* d_in, const int* in_sizes, int n_in,
                              void* d_out, int out_size, void* d_ws, size_t ws_size,
                              hipStream_t stream) {
  (void)in_sizes; (void)n_in; (void)out_size; (void)ws_size;

  const float* x      = (const float*)d_in[0];
  const float* ctx    = (const float*)d_in[1];
  const float* rope   = (const float*)d_in[2];
  const float* wqkv   = (const float*)d_in[3];
  const float* sa_qg  = (const float*)d_in[4];
  const float* sa_qb  = (const float*)d_in[5];
  const float* sa_kg  = (const float*)d_in[6];
  const float* sa_kb  = (const float*)d_in[7];
  const float* sa_wo  = (const float*)d_in[8];
  const float* sa_bo  = (const float*)d_in[9];
  const float* ca_wq  = (const float*)d_in[10];
  const float* ca_wk  = (const float*)d_in[11];
  const float* ca_wv  = (const float*)d_in[12];
  const float* ca_qg  = (const float*)d_in[13];
  const float* ca_qb  = (const float*)d_in[14];
  const float* ca_kg  = (const float*)d_in[15];
  const float* ca_kb  = (const float*)d_in[16];
  const float* ca_wo  = (const float*)d_in[17];
  const float* ca_bo  = (const float*)d_in[18];
  const float* ca_gate= (const float*)d_in[19];
  const float* w1g    = (const float*)d_in[20];
  const float* b1g    = (const float*)d_in[21];
  const float* w1x    = (const float*)d_in[22];
  const float* b1x    = (const float*)d_in[23];
  const float* w2     = (const float*)d_in[24];
  const float* b2     = (const float*)d_in[25];
  const float* ls0    = (const float*)d_in[26];
  const float* ls1    = (const float*)d_in[27];
  const float* ls2    = (const float*)d_in[28];

  char* ws = (char*)d_ws;

  // workspace layout (bytes); peak 218,103,808 (208 MiB), manual reuse
  const long OFF_WQKVT = 0;
  const long OFF_SAWOT = 6291456;
  const long OFF_CAWQT = 8388608;
  const long OFF_CAWKT = 10485760;   // ca_wk^T (2 MB), contiguous with
  const long OFF_CAWVT = 12582912;   // ca_wv^T (2 MB) => stacked 2048-row B
  const long OFF_CAWOT = 14680064;
  const long OFF_W1I   = 16777216;   // 16 MB interleaved w1g/w1x
  const long OFF_W2T   = 33554432;
  const long OFF_XB    = 41943040;   // 16 MB (dead after qkv gemm)
  const long OFF_QC    = OFF_XB;     //   reuse
  const long OFF_CTXB  = 58720256;
  const long OFF_QKV   = 67108864;   // 48 MB (dead after SA attn)
  const long OFF_CAO   = 67108864;
  const long OFF_X2B   = 83886080;
  const long OFF_SG    = 100663296;  // 64 MB (8192x4096 bf16)
  const long OFF_SAO   = 117440512;  // 16 MB SA attn out (dead after step 6)
  const long OFF_KVC   = 117440512;  //   reuse: combined CA K|V (4096x2048)
  const long OFF_X1    = 134217728;
  const long OFF_X1B   = 167772160;  // 16 MB (dead after ca_wq gemm)
  const long OFF_CAVT  = OFF_X1B;    //   reuse: CA V^T tiled (9,437,184)
  const long OFF_X2    = 184549376;  // 33.5 MB (written at step 13)
  const long OFF_SAVT  = OFF_X2;     //   reuse: SA V^T tiled, dead after SA attn

  auto bfp = [&](long off) { return (__hip_bfloat16*)(ws + off); };
  auto ffp = [&](long off) { return (float*)(ws + off); };

  dim3 tb32(32, 8);
  // 1. weight transposes
  transpose_cvt<<<dim3(96, 32), tb32, 0, stream>>>(wqkv,  bfp(OFF_WQKVT), 1024, 3072);
  transpose_cvt<<<dim3(32, 32), tb32, 0, stream>>>(sa_wo, bfp(OFF_SAWOT), 1024, 1024);
  transpose_cvt<<<dim3(32, 32), tb32, 0, stream>>>(ca_wq, bfp(OFF_CAWQT), 1024, 1024);
  transpose_cvt<<<dim3(32, 32), tb32, 0, stream>>>(ca_wk, bfp(OFF_CAWKT), 1024, 1024);
  transpose_cvt<<<dim3(32, 32), tb32, 0, stream>>>(ca_wv, bfp(OFF_CAWVT), 1024, 1024);
  transpose_cvt<<<dim3(32, 32), tb32, 0, stream>>>(ca_wo, bfp(OFF_CAWOT), 1024, 1024);
  transpose_cvt_ilv<<<dim3(128, 32), tb32, 0, stream>>>(w1g, bfp(OFF_W1I), 1024, 4096, 0);
  transpose_cvt_ilv<<<dim3(128, 32), tb32, 0, stream>>>(w1x, bfp(OFF_W1I), 1024, 4096, 16);
  transpose_cvt<<<dim3(32, 128), tb32, 0, stream>>>(w2,   bfp(OFF_W2T), 4096, 1024);

  // 2. activations -> bf16
  cvt_f32_bf16<<<8192, 256, 0, stream>>>(x,   bfp(OFF_XB),   8388608);
  cvt_f32_bf16<<<4096, 256, 0, stream>>>(ctx, bfp(OFF_CTXB), 4194304);

  // 3. qkv = xb @ wqkvT (8192x3072x1024), BM=128 -> 768 blocks = 3/CU
  gemm2ph<128, 0><<<dim3(64, 12), 512, 0, stream>>>(bfp(OFF_XB), bfp(OFF_WQKVT), 8192, 3072, 1024,
                                                    nullptr, bfp(OFF_QKV), nullptr, nullptr, nullptr, nullptr, nullptr);

  // 3b. SA V^T
  transpose_v<<<dim3(64, 2, 64), tb32, 0, stream>>>(bfp(OFF_QKV) + 2048, (long)2048 * 3072, 3072,
                                                    bfp(OFF_SAVT), 2048);

  // 4. SA LN + rope on q,k
  ln_rope<<<65536, 256, 0, stream>>>(bfp(OFF_QKV), rope, sa_qg, sa_qb, sa_kg, sa_kb,
                                     2048, 2, 3 * 1024, 1024, 3, (long)4 * 2048 * 16 * 2);

  // 5. self-attention -> SAO
  attn32<<<1024, 256, 0, stream>>>(bfp(OFF_QKV),        (long)2048 * 3072, 3072,
                                   bfp(OFF_QKV) + 1024, (long)2048 * 3072, 3072,
                                   bfp(OFF_SAVT), bfp(OFF_SAO), 2048, 2048);

  // 6. sa proj + residual
  gemm2ph<128, 1><<<dim3(64, 4), 512, 0, stream>>>(bfp(OFF_SAO), bfp(OFF_SAWOT), 8192, 1024, 1024,
                                                   ffp(OFF_X1), bfp(OFF_X1B), sa_bo, ls0, nullptr, x, nullptr);

  // 7. CA q projection
  gemm2ph<128, 0><<<dim3(64, 4), 512, 0, stream>>>(bfp(OFF_X1B), bfp(OFF_CAWQT), 8192, 1024, 1024,
                                                   nullptr, bfp(OFF_QC), nullptr, nullptr, nullptr, nullptr, nullptr);
  // 8. CA k|v combined: KVC = ctx @ [wk|wv] (4096x2048x1024, 256 blocks)
  gemm2ph<128, 0><<<dim3(32, 8), 512, 0, stream>>>(bfp(OFF_CTXB), bfp(OFF_CAWKT), 4096, 2048, 1024,
                                                   nullptr, bfp(OFF_KVC), nullptr, nullptr, nullptr, nullptr, nullptr);

  // 9b. CA V^T from V half of KVC (row stride 2048)
  transpose_v<<<dim3(32, 2, 64), tb32, 0, stream>>>(bfp(OFF_KVC) + 1024, (long)1024 * 2048, 2048,
                                                    bfp(OFF_CAVT), 1024);

  // 10-11. CA LN (+rope on q only); K half of KVC LN'd in place
  ln_rope<<<32768, 256, 0, stream>>>(bfp(OFF_QC), rope, ca_qg, ca_qb, ca_qg, ca_qb,
                                     2048, 1, 1024, 0, 1, (long)4 * 2048 * 16);
  ln_rope<<<16384, 256, 0, stream>>>(bfp(OFF_KVC), rope, ca_kg, ca_kb, ca_kg, ca_kb,
                                     1024, 1, 2048, 0, 0, (long)4 * 1024 * 16);

  // 12. cross-attention (K from KVC, row stride 2048)
  attn32<<<1024, 256, 0, stream>>>(bfp(OFF_QC), (long)2048 * 1024, 1024,
                                   bfp(OFF_KVC), (long)1024 * 2048, 2048,
                                   bfp(OFF_CAVT), bfp(OFF_CAO), 2048, 1024);

  // 13. ca proj: x2 = ls1*((ca@wo + bo)*tanh(gate)) + x1
  gemm2ph<128, 2><<<dim3(64, 4), 512, 0, stream>>>(bfp(OFF_CAO), bfp(OFF_CAWOT), 8192, 1024, 1024,
                                                   ffp(OFF_X2), bfp(OFF_X2B), ca_bo, ls1, ca_gate, ffp(OFF_X1), nullptr);

  // 14. FUSED MLP up: sg = silu(x2b@w1g + b1g) * (x2b@w1x + b1x), EPI=6
  gemm2ph<256, 6><<<dim3(32, 32), 512, 0, stream>>>(bfp(OFF_X2B), bfp(OFF_W1I), 8192, 8192, 1024,
                                                    nullptr, bfp(OFF_SG), b1g, nullptr, b1x, nullptr, nullptr);

  // 16. out = ls2*(sg @ w2T + b2) + x2
  gemm2ph<128, 5><<<dim3(64, 4), 512, 0, stream>>>(bfp(OFF_SG), bfp(OFF_W2T), 8192, 1024, 4096,
                                                   (float*)d_out, nullptr, b2, ls2, nullptr, ffp(OFF_X2), nullptr);
}